// Round 1
// 194.640 us; speedup vs baseline: 1.0386x; 1.0386x over previous
//
#include <hip/hip_runtime.h>
#include <stdint.h>

typedef unsigned short u16;
typedef __bf16 bf16x8 __attribute__((ext_vector_type(8)));
typedef __bf16 bf16x4v __attribute__((ext_vector_type(4)));
typedef float f32x4 __attribute__((ext_vector_type(4)));

typedef __attribute__((address_space(3))) uint32_t lds_u32;
typedef __attribute__((address_space(1))) uint32_t glb_u32;

__device__ __forceinline__ f32x4 mfma16(bf16x8 a, bf16x8 b, f32x4 c) {
    return __builtin_amdgcn_mfma_f32_16x16x32_bf16(a, b, c, 0, 0, 0);
}

// 4x f32 -> bf16 via native cvt (RNE), reinterpreted as ushort4
__device__ __forceinline__ ushort4 pk4(float a, float b, float c, float d) {
    bf16x4v v;
    v[0] = (__bf16)a; v[1] = (__bf16)b; v[2] = (__bf16)c; v[3] = (__bf16)d;
    union { bf16x4v v; ushort4 u; } cv; cv.v = v; return cv.u;
}

// raw v_exp_f32 (skip ocml wrapper)
__device__ __forceinline__ float fexp2(float x) {
    return __builtin_amdgcn_exp2f(x);
}

// async global->LDS, 16B per lane (LDS dest = wave base + lane*16)
__device__ __forceinline__ void async16(const u16* g, u16* l) {
    __builtin_amdgcn_global_load_lds((glb_u32*)(uintptr_t)(const void*)g,
                                     (lds_u32*)l, 16, 0, 0);
}

// ---------------------------------------------------------------------------
// fp32 -> bf16 casts (unchanged)
// ---------------------------------------------------------------------------
__global__ __launch_bounds__(256) void cast_all(
    const float* __restrict__ x,
    const float* __restrict__ w0, const float* __restrict__ w1,
    const float* __restrict__ w2, const float* __restrict__ w3,
    u16* __restrict__ xo, u16* __restrict__ o0, u16* __restrict__ o1,
    u16* __restrict__ o2, u16* __restrict__ o3)
{
    const int s = blockIdx.y;
    const int i = (blockIdx.x * 256 + threadIdx.x) * 4;
    if (s == 0) {
#pragma unroll
        for (int c = 0; c < 4; ++c) {
            const int j = i + c * (1 << 20);
            float4 v = *(const float4*)(x + j);
            *(ushort4*)(xo + j) = pk4(v.x, v.y, v.z, v.w);
        }
    } else {
        const float* in = s == 1 ? w0 : (s == 2 ? w1 : (s == 3 ? w2 : w3));
        u16* out       = s == 1 ? o0 : (s == 2 ? o1 : (s == 3 ? o2 : o3));
        float4 v = *(const float4*)(in + i);
        *(ushort4*)(out + i) = pk4(v.x, v.y, v.z, v.w);
    }
}

// ---------------------------------------------------------------------------
// QKV GEMM (unchanged from round 13)
// ---------------------------------------------------------------------------
__global__ __launch_bounds__(256) void gemm_qkv(
    const u16* __restrict__ A,
    const u16* __restrict__ W0, const u16* __restrict__ W1, const u16* __restrict__ W2,
    const float* __restrict__ B0, const float* __restrict__ B1, const float* __restrict__ B2,
    u16* __restrict__ O0, u16* __restrict__ O1,
    u16* __restrict__ VT,
    int M, int N, int K)
{
    const int x = blockIdx.x & 7;
    const int L = blockIdx.x >> 3;                 // 0..95
    const int tm = (8 * (x >> 1) + (L & 7)) << 7;  // 32 tm tiles
    const int tnsel = 12 * (x & 1) + (L >> 3);     // 0..23
    const int sel = tnsel >> 3;
    const int tn  = (tnsel & 7) << 7;

    const u16* W      = sel == 0 ? W0 : (sel == 1 ? W1 : W2);
    const float* bias = sel == 0 ? B0 : (sel == 1 ? B1 : B2);
    u16* O            = sel == 0 ? O0 : O1;        // sel==2 -> VT path

    __shared__ __attribute__((aligned(16))) u16 As[128 * 64];
    __shared__ __attribute__((aligned(16))) u16 Bs[128 * 64];
    u16 (*Tb)[136] = (u16 (*)[136])As;             // union: post-K-loop only

    const int tid  = threadIdx.x;
    const int lane = tid & 63;
    const int w    = tid >> 6;
    const int l15  = lane & 15;
    const int quad = lane >> 4;

    const int wm = (w >> 1) << 6;
    const int wn = (w & 1) << 6;

    f32x4 acc[4][4];
#pragma unroll
    for (int i = 0; i < 4; ++i)
#pragma unroll
        for (int j = 0; j < 4; ++j) acc[i][j] = f32x4{0.f, 0.f, 0.f, 0.f};

    const int lr  = lane >> 3;                     // 0..7
    const int lcc = lane & 7;                      // dest chunk
    const int scc = lcc ^ lr;                      // source chunk (row&7 == lr)
    const u16* Ag = A + (size_t)(tm + 32 * w + lr) * K + scc * 8;
    const u16* Wg = W + (size_t)(tn + 32 * w + lr) * K + scc * 8;
    u16* Al = &As[(32 * w + lr) * 64 + lcc * 8];
    u16* Bl = &Bs[(32 * w + lr) * 64 + lcc * 8];

    for (int k0 = 0; k0 < K; k0 += 64) {
        __syncthreads();
#pragma unroll
        for (int m = 0; m < 4; ++m) {
            async16(Ag + k0 + (size_t)m * 8 * K, Al + m * 512);
            async16(Wg + k0 + (size_t)m * 8 * K, Bl + m * 512);
        }
        asm volatile("s_waitcnt vmcnt(0)" ::: "memory");
        __syncthreads();

#pragma unroll
        for (int kk = 0; kk < 2; ++kk) {
            bf16x8 a[4], b[4];
#pragma unroll
            for (int i = 0; i < 4; ++i) {
                const int r  = wm + 16 * i + l15;
                const int sl = (kk * 4 + quad) ^ (r & 7);
                a[i] = *(const bf16x8*)&As[r * 64 + sl * 8];
            }
#pragma unroll
            for (int j = 0; j < 4; ++j) {
                const int r  = wn + 16 * j + l15;
                const int sl = (kk * 4 + quad) ^ (r & 7);
                b[j] = *(const bf16x8*)&Bs[r * 64 + sl * 8];
            }
#pragma unroll
            for (int i = 0; i < 4; ++i)
#pragma unroll
                for (int j = 0; j < 4; ++j)
                    acc[i][j] = mfma16(a[i], b[j], acc[i][j]);
        }
    }

    if (sel == 2) {
        const int bb = tm >> 11;
        const int s0 = tm & 2047;
        const size_t vtb = ((size_t)bb << 10) + tn;
        for (int c32 = 0; c32 < 128; c32 += 32) {
            __syncthreads();
            if ((c32 >> 6) == (wn >> 6)) {
                const int j0 = (c32 >> 4) & 2;
#pragma unroll
                for (int jj = 0; jj < 2; ++jj) {
                    const int j  = j0 + jj;
                    const int cc = jj * 16 + l15;
                    const float bj = bias[tn + wn + 16 * j + l15];
#pragma unroll
                    for (int i = 0; i < 4; ++i) {
                        const int rr = wm + 16 * i + quad * 4;
                        *(ushort4*)&Tb[cc][rr] =
                            pk4(acc[i][j][0] + bj, acc[i][j][1] + bj,
                                acc[i][j][2] + bj, acc[i][j][3] + bj);
                    }
                }
            }
            __syncthreads();
            {
                const int c  = tid >> 3;
                const int ss = (tid & 7) * 16;
                uint4 v0 = *(const uint4*)&Tb[c][ss];
                uint4 v1 = *(const uint4*)&Tb[c][ss + 8];
                u16* dst = &VT[(vtb + c32 + c) * 2048 + s0 + ss];
                *(uint4*)dst       = v0;
                *(uint4*)(dst + 8) = v1;
            }
        }
    } else {
#pragma unroll
        for (int j = 0; j < 4; ++j) {
            const int col = tn + wn + 16 * j + l15;
            const float bj = bias[col];
#pragma unroll
            for (int i = 0; i < 4; ++i) {
                const int row = tm + wm + 16 * i + quad * 4;
#pragma unroll
                for (int r = 0; r < 4; ++r) {
                    union { float f; unsigned u; } v; v.f = acc[i][j][r] + bj;
                    unsigned rn = v.u + 0x7FFFu + ((v.u >> 16) & 1u);
                    O[(size_t)(row + r) * N + col] = (u16)(rn >> 16);
                }
            }
        }
    }
}

// ---------------------------------------------------------------------------
// Output projection GEMM (unchanged from round 13)
// ---------------------------------------------------------------------------
__global__ __launch_bounds__(256) void gemm_out64(
    const u16* __restrict__ A, const u16* __restrict__ W,
    const float* __restrict__ bias, float* __restrict__ O,
    int M, int N, int K)
{
    __shared__ __attribute__((aligned(16))) u16 As[128 * 64];
    __shared__ __attribute__((aligned(16))) u16 Bs[64 * 64];

    const int x = blockIdx.x & 7;
    const int L = blockIdx.x >> 3;                 // 0..63
    const int tm = (8 * (x >> 1) + (L & 7)) << 7;  // 32 tiles
    const int tn = (8 * (x & 1) + (L >> 3)) << 6;  // 16 tiles

    const int tid  = threadIdx.x;
    const int lane = tid & 63;
    const int w    = tid >> 6;
    const int l15  = lane & 15;
    const int quad = lane >> 4;

    const int wm = (w >> 1) << 6;
    const int wn = (w & 1) << 5;

    f32x4 acc[4][2];
#pragma unroll
    for (int i = 0; i < 4; ++i)
#pragma unroll
        for (int j = 0; j < 2; ++j) acc[i][j] = f32x4{0.f, 0.f, 0.f, 0.f};

    const int lr  = lane >> 3;
    const int lcc = lane & 7;
    const int scc = lcc ^ lr;
    const u16* Ag = A + (size_t)(tm + 32 * w + lr) * K + scc * 8;
    const u16* Wg = W + (size_t)(tn + 16 * w + lr) * K + scc * 8;
    u16* Al = &As[(32 * w + lr) * 64 + lcc * 8];
    u16* Bl = &Bs[(16 * w + lr) * 64 + lcc * 8];

    for (int k0 = 0; k0 < K; k0 += 64) {
        __syncthreads();
#pragma unroll
        for (int m = 0; m < 4; ++m)
            async16(Ag + k0 + (size_t)m * 8 * K, Al + m * 512);
#pragma unroll
        for (int m = 0; m < 2; ++m)
            async16(Wg + k0 + (size_t)m * 8 * K, Bl + m * 512);
        asm volatile("s_waitcnt vmcnt(0)" ::: "memory");
        __syncthreads();

#pragma unroll
        for (int kk = 0; kk < 2; ++kk) {
            bf16x8 a[4], b[2];
#pragma unroll
            for (int i = 0; i < 4; ++i) {
                const int r  = wm + 16 * i + l15;
                const int sl = (kk * 4 + quad) ^ (r & 7);
                a[i] = *(const bf16x8*)&As[r * 64 + sl * 8];
            }
#pragma unroll
            for (int j = 0; j < 2; ++j) {
                const int r  = wn + 16 * j + l15;
                const int sl = (kk * 4 + quad) ^ (r & 7);
                b[j] = *(const bf16x8*)&Bs[r * 64 + sl * 8];
            }
#pragma unroll
            for (int i = 0; i < 4; ++i)
#pragma unroll
                for (int j = 0; j < 2; ++j)
                    acc[i][j] = mfma16(a[i], b[j], acc[i][j]);
        }
    }

#pragma unroll
    for (int j = 0; j < 2; ++j) {
        const int col = tn + wn + 16 * j + l15;
        const float bj = bias[col];
#pragma unroll
        for (int i = 0; i < 4; ++i) {
            const int row = tm + wm + 16 * i + quad * 4;
#pragma unroll
            for (int r = 0; r < 4; ++r)
                O[(size_t)(row + r) * N + col] = acc[i][j][r] + bj;
        }
    }
}

// ---------------------------------------------------------------------------
// attn7: round-14 rework of attn6.
//  * K/V LDS swizzle fixed: chunk slot = c ^ ((r>>1)&3) instead of c ^ (r&3).
//    Old scheme: rows {0,4,8,12} of a 16-lane read phase hit the same 16B
//    bank window -> 4-way conflict on every ds_read_b128. New: 2-way (free).
//  * Pt: stride 72 -> 64 with chunk-XOR swizzle (chunk ^ (row&7)); both the
//    ushort4 P-writes and b128 B-frag reads become 2-way. LDS 51200->49152.
//  * softmax: raw v_exp_f32 (__builtin_amdgcn_exp2f), causal mask peeled
//    into compile-time masked/unmasked variants behind wave-uniform
//    branches (mask select only runs on the 1-2 diagonal tiles), rs
//    accumulated in f32x4 (4 chains instead of a 16-deep serial chain).
//  * V frags read once, shared by H and L PV explicitly.
//  * s_setprio(1) around QK and PV MFMA clusters (T5).
// ---------------------------------------------------------------------------
__device__ __forceinline__ bf16x8 rdt(const u16* base, int t, int l15, int cc) {
    const int r = t * 16 + l15;
    const int c = (cc & 3) ^ ((r >> 1) & 3);
    return *(const bf16x8*)(base + (cc >> 2) * 2048 + r * 32 + c * 8);
}

#define QK_EXP(Z, PROW, QG, MASKED, RSV, KB)                                   \
    do {                                                                       \
        _Pragma("unroll")                                                      \
        for (int t = 0; t < 4; ++t) {                                          \
            float e0 = fexp2(fmaf((Z)[t][0], SC, -16.0f));                     \
            float e1 = fexp2(fmaf((Z)[t][1], SC, -16.0f));                     \
            float e2 = fexp2(fmaf((Z)[t][2], SC, -16.0f));                     \
            float e3 = fexp2(fmaf((Z)[t][3], SC, -16.0f));                     \
            if (MASKED) {                                                      \
                const int kb = (KB) + t * 16 + quad * 4;                       \
                if (kb + 0 > (QG)) e0 = 0.f;                                   \
                if (kb + 1 > (QG)) e1 = 0.f;                                   \
                if (kb + 2 > (QG)) e2 = 0.f;                                   \
                if (kb + 3 > (QG)) e3 = 0.f;                                   \
            }                                                                  \
            (RSV)[0] += e0; (RSV)[1] += e1;                                    \
            (RSV)[2] += e2; (RSV)[3] += e3;                                    \
            *(ushort4*)((PROW) + (((2 * t + whi) ^ sl7) << 3) + woff) =        \
                pk4(e0, e1, e2, e3);                                           \
        }                                                                      \
    } while (0)

__global__ __launch_bounds__(256) void attn7(
    const u16* __restrict__ Q, const u16* __restrict__ Kb,
    const u16* __restrict__ VT, u16* __restrict__ ctx)
{
    __shared__ __attribute__((aligned(16))) u16 Kt[2][4096];
    __shared__ __attribute__((aligned(16))) u16 Vt[2][4096];
    __shared__ __attribute__((aligned(16))) u16 Pt[4][32][64];

    const int tid  = threadIdx.x;
    const int lane = tid & 63;
    const int wid  = tid >> 6;
    const int l15  = lane & 15;
    const int quad = lane >> 4;
    const int sl7  = l15 & 7;
    const int whi  = quad >> 1;
    const int woff = (quad & 1) * 4;

    const int hb = blockIdx.x & 31;
    const int h  = hb & 15, b = hb >> 4;
    const int ti = blockIdx.x >> 5;
    const int g  = (ti & 1) ? (15 - (ti >> 1)) : (ti >> 1);

    const int sL = 4 * g + wid, sH = 127 - sL;
    const int KL = g, KH = 31 - g;

    const size_t rowbase = (size_t)b * 2048;
    const int cbase = h * 64;
    const u16* kbase = Kb + rowbase * 1024 + cbase;
    const u16* vbase = VT + ((size_t)b * 1024 + cbase) * 2048;

    const int qgL = sL * 16 + l15, qgH = sH * 16 + l15;
    const u16* qpL = Q + (rowbase + qgL) * 1024 + cbase + quad * 8;
    const u16* qpH = Q + (rowbase + qgH) * 1024 + cbase + quad * 8;
    const bf16x8 qL0 = *(const bf16x8*)qpL, qL1 = *(const bf16x8*)(qpL + 32);
    const bf16x8 qH0 = *(const bf16x8*)qpH, qH1 = *(const bf16x8*)(qpH + 32);

    // staging: row sr = tid>>2, dest chunk tid&3 (linear); source chunk
    // permuted (c ^ ((sr>>1)&3)) so rdt's 16-lane read phases are 2-way.
    const int sr  = tid >> 2;
    const int sc0 = (((tid & 3) ^ ((sr >> 1) & 3)) << 3);
    const u16* kg = kbase + (size_t)sr * 1024 + sc0;
    const u16* vg = vbase + (size_t)sr * 2048 + sc0;

    f32x4 oL[4], oH[4];
#pragma unroll
    for (int i = 0; i < 4; ++i) { oL[i] = f32x4{0,0,0,0}; oH[i] = f32x4{0,0,0,0}; }
    f32x4 rsLv = {0,0,0,0}, rsHv = {0,0,0,0};
    const float SC = 0.18033688011112042f;

    u16 (*ptw)[64] = Pt[wid];
    u16* const prH = &ptw[16 + l15][0];
    u16* const prL = &ptw[l15][0];

    async16(kg,      &Kt[0][tid * 8]);
    async16(kg + 32, &Kt[0][2048 + tid * 8]);
    async16(vg,      &Vt[0][tid * 8]);
    async16(vg + 32, &Vt[0][2048 + tid * 8]);

    for (int kt = 0; kt <= KH; ++kt) {
        const int cur = kt & 1, nxt = cur ^ 1;
        asm volatile("s_waitcnt vmcnt(0)" ::: "memory");
        __syncthreads();
        if (kt < KH) {
            const u16* kgn = kg + (size_t)(kt + 1) * 65536;
            const u16* vgn = vg + (kt + 1) * 64;
            async16(kgn,      &Kt[nxt][tid * 8]);
            async16(kgn + 32, &Kt[nxt][2048 + tid * 8]);
            async16(vgn,      &Vt[nxt][tid * 8]);
            async16(vgn + 32, &Vt[nxt][2048 + tid * 8]);
        }
        const u16* KT = Kt[cur];
        const u16* VL = Vt[cur];
        const bool doL = (kt <= KL);
        const bool mH = (kt == KH), mL = (kt == KL);

        // ---- QK^T into registers ----
        f32x4 zH[4], zL[4];
        __builtin_amdgcn_s_setprio(1);
        if (doL) {
#pragma unroll
            for (int t = 0; t < 4; ++t) {
                const bf16x8 kA = rdt(KT, t, l15, quad);
                const bf16x8 kB = rdt(KT, t, l15, quad + 4);
                f32x4 zh = {0,0,0,0};
                zh = mfma16(kA, qH0, zh);
                zh = mfma16(kB, qH1, zh);
                zH[t] = zh;
                f32x4 zl = {0,0,0,0};
                zl = mfma16(kA, qL0, zl);
                zl = mfma16(kB, qL1, zl);
                zL[t] = zl;
            }
        } else {
#pragma unroll
            for (int t = 0; t < 4; ++t) {
                const bf16x8 kA = rdt(KT, t, l15, quad);
                const bf16x8 kB = rdt(KT, t, l15, quad + 4);
                f32x4 zh = {0,0,0,0};
                zh = mfma16(kA, qH0, zh);
                zh = mfma16(kB, qH1, zh);
                zH[t] = zh;
            }
        }
        __builtin_amdgcn_s_setprio(0);

        // ---- exp + pack into Pt (mask peeled: only diagonal tiles pay) ----
        const int ktb = kt * 64;
        if (mH) QK_EXP(zH, prH, qgH, 1, rsHv, ktb);
        else    QK_EXP(zH, prH, qgH, 0, rsHv, ktb);
        if (doL) {
            if (mL) QK_EXP(zL, prL, qgL, 1, rsLv, ktb);
            else    QK_EXP(zL, prL, qgL, 0, rsLv, ktb);
        }

        // ---- PV ----
        const bf16x8 bH0 = *(const bf16x8*)(prH + ((quad ^ sl7) << 3));
        const bf16x8 bH1 = *(const bf16x8*)(prH + (((quad | 4) ^ sl7) << 3));
        if (doL) {
            const bf16x8 bL0 = *(const bf16x8*)(prL + ((quad ^ sl7) << 3));
            const bf16x8 bL1 = *(const bf16x8*)(prL + (((quad | 4) ^ sl7) << 3));
            __builtin_amdgcn_s_setprio(1);
#pragma unroll
            for (int t = 0; t < 4; ++t) {
                const bf16x8 vA = rdt(VL, t, l15, quad);
                const bf16x8 vB = rdt(VL, t, l15, quad + 4);
                oH[t] = mfma16(vA, bH0, oH[t]);
                oH[t] = mfma16(vB, bH1, oH[t]);
                oL[t] = mfma16(vA, bL0, oL[t]);
                oL[t] = mfma16(vB, bL1, oL[t]);
            }
            __builtin_amdgcn_s_setprio(0);
        } else {
            __builtin_amdgcn_s_setprio(1);
#pragma unroll
            for (int t = 0; t < 4; ++t) {
                const bf16x8 vA = rdt(VL, t, l15, quad);
                const bf16x8 vB = rdt(VL, t, l15, quad + 4);
                oH[t] = mfma16(vA, bH0, oH[t]);
                oH[t] = mfma16(vB, bH1, oH[t]);
            }
            __builtin_amdgcn_s_setprio(0);
        }
    }

    float rsH = (rsHv[0] + rsHv[1]) + (rsHv[2] + rsHv[3]);
    float rsL = (rsLv[0] + rsLv[1]) + (rsLv[2] + rsLv[3]);
    rsH += __shfl_xor(rsH, 16); rsH += __shfl_xor(rsH, 32);
    rsL += __shfl_xor(rsL, 16); rsL += __shfl_xor(rsL, 32);
    const float iH = 1.0f / rsH, iL = 1.0f / rsL;
#pragma unroll
    for (int t = 0; t < 4; ++t) {
        *(ushort4*)&ctx[(rowbase + qgL) * 1024 + cbase + t * 16 + quad * 4] =
            pk4(oL[t][0] * iL, oL[t][1] * iL, oL[t][2] * iL, oL[t][3] * iL);
        *(ushort4*)&ctx[(rowbase + qgH) * 1024 + cbase + t * 16 + quad * 4] =
            pk4(oH[t][0] * iH, oH[t][1] * iH, oH[t][2] * iH, oH[t][3] * iH);
    }
}

extern "C" void kernel_launch(void* const* d_in, const int* in_sizes, int n_in,
                              void* d_out, int out_size, void* d_ws, size_t ws_size,
                              hipStream_t stream) {
    const float* x  = (const float*)d_in[0];
    const float* Wq = (const float*)d_in[1];
    const float* bq = (const float*)d_in[2];
    const float* Wk = (const float*)d_in[3];
    const float* bk = (const float*)d_in[4];
    const float* Wv = (const float*)d_in[5];
    const float* bv = (const float*)d_in[6];
    const float* Wo = (const float*)d_in[7];
    const float* bo = (const float*)d_in[8];
    float* out = (float*)d_out;

    const int N = 1024, K = 1024;
    const int M = in_sizes[0] / K;           // 4096
    const size_t MN = (size_t)M * N;
    const size_t WN = (size_t)N * K;

    u16* xb  = (u16*)d_ws;
    u16* wqb = xb  + MN;
    u16* wkb = wqb + WN;
    u16* wvb = wkb + WN;
    u16* wob = wvb + WN;
    u16* q   = wob + WN;
    u16* kb  = q   + MN;
    u16* vt  = kb  + MN;                     // V^T: [b*1024 + h*64 + d][s]
    u16* ctx = q;                            // alias: disjoint per-wave strips

    cast_all<<<dim3(1024, 5), 256, 0, stream>>>(
        x, Wq, Wk, Wv, Wo, xb, wqb, wkb, wvb, wob);

    gemm_qkv<<<dim3(768), 256, 0, stream>>>(
        xb, wqb, wkb, wvb, bq, bk, bv, q, kb, vt, M, N, K);

    attn7<<<dim3(512), 256, 0, stream>>>(q, kb, vt, ctx);

    gemm_out64<<<dim3(512), 256, 0, stream>>>(
        ctx, wob, bo, out, M, N, K);
}

// Round 2
// 192.804 us; speedup vs baseline: 1.0484x; 1.0095x over previous
//
#include <hip/hip_runtime.h>
#include <stdint.h>

typedef unsigned short u16;
typedef __bf16 bf16x8 __attribute__((ext_vector_type(8)));
typedef __bf16 bf16x4v __attribute__((ext_vector_type(4)));
typedef float f32x4 __attribute__((ext_vector_type(4)));

typedef __attribute__((address_space(3))) uint32_t lds_u32;
typedef __attribute__((address_space(1))) uint32_t glb_u32;

__device__ __forceinline__ f32x4 mfma16(bf16x8 a, bf16x8 b, f32x4 c) {
    return __builtin_amdgcn_mfma_f32_16x16x32_bf16(a, b, c, 0, 0, 0);
}

// 4x f32 -> bf16 via native cvt (RNE), reinterpreted as ushort4
__device__ __forceinline__ ushort4 pk4(float a, float b, float c, float d) {
    bf16x4v v;
    v[0] = (__bf16)a; v[1] = (__bf16)b; v[2] = (__bf16)c; v[3] = (__bf16)d;
    union { bf16x4v v; ushort4 u; } cv; cv.v = v; return cv.u;
}

// raw v_exp_f32 (skip ocml wrapper)
__device__ __forceinline__ float fexp2(float x) {
    return __builtin_amdgcn_exp2f(x);
}

// async global->LDS, 16B per lane (LDS dest = wave base + lane*16)
__device__ __forceinline__ void async16(const u16* g, u16* l) {
    __builtin_amdgcn_global_load_lds((glb_u32*)(uintptr_t)(const void*)g,
                                     (lds_u32*)l, 16, 0, 0);
}

// ---------------------------------------------------------------------------
// fp32 -> bf16 casts (unchanged)
// ---------------------------------------------------------------------------
__global__ __launch_bounds__(256) void cast_all(
    const float* __restrict__ x,
    const float* __restrict__ w0, const float* __restrict__ w1,
    const float* __restrict__ w2, const float* __restrict__ w3,
    u16* __restrict__ xo, u16* __restrict__ o0, u16* __restrict__ o1,
    u16* __restrict__ o2, u16* __restrict__ o3)
{
    const int s = blockIdx.y;
    const int i = (blockIdx.x * 256 + threadIdx.x) * 4;
    if (s == 0) {
#pragma unroll
        for (int c = 0; c < 4; ++c) {
            const int j = i + c * (1 << 20);
            float4 v = *(const float4*)(x + j);
            *(ushort4*)(xo + j) = pk4(v.x, v.y, v.z, v.w);
        }
    } else {
        const float* in = s == 1 ? w0 : (s == 2 ? w1 : (s == 3 ? w2 : w3));
        u16* out       = s == 1 ? o0 : (s == 2 ? o1 : (s == 3 ? o2 : o3));
        float4 v = *(const float4*)(in + i);
        *(ushort4*)(out + i) = pk4(v.x, v.y, v.z, v.w);
    }
}

// ---------------------------------------------------------------------------
// QKV GEMM (unchanged)
// ---------------------------------------------------------------------------
__global__ __launch_bounds__(256) void gemm_qkv(
    const u16* __restrict__ A,
    const u16* __restrict__ W0, const u16* __restrict__ W1, const u16* __restrict__ W2,
    const float* __restrict__ B0, const float* __restrict__ B1, const float* __restrict__ B2,
    u16* __restrict__ O0, u16* __restrict__ O1,
    u16* __restrict__ VT,
    int M, int N, int K)
{
    const int x = blockIdx.x & 7;
    const int L = blockIdx.x >> 3;                 // 0..95
    const int tm = (8 * (x >> 1) + (L & 7)) << 7;  // 32 tm tiles
    const int tnsel = 12 * (x & 1) + (L >> 3);     // 0..23
    const int sel = tnsel >> 3;
    const int tn  = (tnsel & 7) << 7;

    const u16* W      = sel == 0 ? W0 : (sel == 1 ? W1 : W2);
    const float* bias = sel == 0 ? B0 : (sel == 1 ? B1 : B2);
    u16* O            = sel == 0 ? O0 : O1;        // sel==2 -> VT path

    __shared__ __attribute__((aligned(16))) u16 As[128 * 64];
    __shared__ __attribute__((aligned(16))) u16 Bs[128 * 64];
    u16 (*Tb)[136] = (u16 (*)[136])As;             // union: post-K-loop only

    const int tid  = threadIdx.x;
    const int lane = tid & 63;
    const int w    = tid >> 6;
    const int l15  = lane & 15;
    const int quad = lane >> 4;

    const int wm = (w >> 1) << 6;
    const int wn = (w & 1) << 6;

    f32x4 acc[4][4];
#pragma unroll
    for (int i = 0; i < 4; ++i)
#pragma unroll
        for (int j = 0; j < 4; ++j) acc[i][j] = f32x4{0.f, 0.f, 0.f, 0.f};

    const int lr  = lane >> 3;                     // 0..7
    const int lcc = lane & 7;                      // dest chunk
    const int scc = lcc ^ lr;                      // source chunk (row&7 == lr)
    const u16* Ag = A + (size_t)(tm + 32 * w + lr) * K + scc * 8;
    const u16* Wg = W + (size_t)(tn + 32 * w + lr) * K + scc * 8;
    u16* Al = &As[(32 * w + lr) * 64 + lcc * 8];
    u16* Bl = &Bs[(32 * w + lr) * 64 + lcc * 8];

    for (int k0 = 0; k0 < K; k0 += 64) {
        __syncthreads();
#pragma unroll
        for (int m = 0; m < 4; ++m) {
            async16(Ag + k0 + (size_t)m * 8 * K, Al + m * 512);
            async16(Wg + k0 + (size_t)m * 8 * K, Bl + m * 512);
        }
        asm volatile("s_waitcnt vmcnt(0)" ::: "memory");
        __syncthreads();

#pragma unroll
        for (int kk = 0; kk < 2; ++kk) {
            bf16x8 a[4], b[4];
#pragma unroll
            for (int i = 0; i < 4; ++i) {
                const int r  = wm + 16 * i + l15;
                const int sl = (kk * 4 + quad) ^ (r & 7);
                a[i] = *(const bf16x8*)&As[r * 64 + sl * 8];
            }
#pragma unroll
            for (int j = 0; j < 4; ++j) {
                const int r  = wn + 16 * j + l15;
                const int sl = (kk * 4 + quad) ^ (r & 7);
                b[j] = *(const bf16x8*)&Bs[r * 64 + sl * 8];
            }
#pragma unroll
            for (int i = 0; i < 4; ++i)
#pragma unroll
                for (int j = 0; j < 4; ++j)
                    acc[i][j] = mfma16(a[i], b[j], acc[i][j]);
        }
    }

    if (sel == 2) {
        const int bb = tm >> 11;
        const int s0 = tm & 2047;
        const size_t vtb = ((size_t)bb << 10) + tn;
        for (int c32 = 0; c32 < 128; c32 += 32) {
            __syncthreads();
            if ((c32 >> 6) == (wn >> 6)) {
                const int j0 = (c32 >> 4) & 2;
#pragma unroll
                for (int jj = 0; jj < 2; ++jj) {
                    const int j  = j0 + jj;
                    const int cc = jj * 16 + l15;
                    const float bj = bias[tn + wn + 16 * j + l15];
#pragma unroll
                    for (int i = 0; i < 4; ++i) {
                        const int rr = wm + 16 * i + quad * 4;
                        *(ushort4*)&Tb[cc][rr] =
                            pk4(acc[i][j][0] + bj, acc[i][j][1] + bj,
                                acc[i][j][2] + bj, acc[i][j][3] + bj);
                    }
                }
            }
            __syncthreads();
            {
                const int c  = tid >> 3;
                const int ss = (tid & 7) * 16;
                uint4 v0 = *(const uint4*)&Tb[c][ss];
                uint4 v1 = *(const uint4*)&Tb[c][ss + 8];
                u16* dst = &VT[(vtb + c32 + c) * 2048 + s0 + ss];
                *(uint4*)dst       = v0;
                *(uint4*)(dst + 8) = v1;
            }
        }
    } else {
#pragma unroll
        for (int j = 0; j < 4; ++j) {
            const int col = tn + wn + 16 * j + l15;
            const float bj = bias[col];
#pragma unroll
            for (int i = 0; i < 4; ++i) {
                const int row = tm + wm + 16 * i + quad * 4;
#pragma unroll
                for (int r = 0; r < 4; ++r) {
                    union { float f; unsigned u; } v; v.f = acc[i][j][r] + bj;
                    unsigned rn = v.u + 0x7FFFu + ((v.u >> 16) & 1u);
                    O[(size_t)(row + r) * N + col] = (u16)(rn >> 16);
                }
            }
        }
    }
}

// ---------------------------------------------------------------------------
// Output projection GEMM (unchanged)
// ---------------------------------------------------------------------------
__global__ __launch_bounds__(256) void gemm_out64(
    const u16* __restrict__ A, const u16* __restrict__ W,
    const float* __restrict__ bias, float* __restrict__ O,
    int M, int N, int K)
{
    __shared__ __attribute__((aligned(16))) u16 As[128 * 64];
    __shared__ __attribute__((aligned(16))) u16 Bs[64 * 64];

    const int x = blockIdx.x & 7;
    const int L = blockIdx.x >> 3;                 // 0..63
    const int tm = (8 * (x >> 1) + (L & 7)) << 7;  // 32 tiles
    const int tn = (8 * (x & 1) + (L >> 3)) << 6;  // 16 tiles

    const int tid  = threadIdx.x;
    const int lane = tid & 63;
    const int w    = tid >> 6;
    const int l15  = lane & 15;
    const int quad = lane >> 4;

    const int wm = (w >> 1) << 6;
    const int wn = (w & 1) << 5;

    f32x4 acc[4][2];
#pragma unroll
    for (int i = 0; i < 4; ++i)
#pragma unroll
        for (int j = 0; j < 2; ++j) acc[i][j] = f32x4{0.f, 0.f, 0.f, 0.f};

    const int lr  = lane >> 3;
    const int lcc = lane & 7;
    const int scc = lcc ^ lr;
    const u16* Ag = A + (size_t)(tm + 32 * w + lr) * K + scc * 8;
    const u16* Wg = W + (size_t)(tn + 16 * w + lr) * K + scc * 8;
    u16* Al = &As[(32 * w + lr) * 64 + lcc * 8];
    u16* Bl = &Bs[(16 * w + lr) * 64 + lcc * 8];

    for (int k0 = 0; k0 < K; k0 += 64) {
        __syncthreads();
#pragma unroll
        for (int m = 0; m < 4; ++m)
            async16(Ag + k0 + (size_t)m * 8 * K, Al + m * 512);
#pragma unroll
        for (int m = 0; m < 2; ++m)
            async16(Wg + k0 + (size_t)m * 8 * K, Bl + m * 512);
        asm volatile("s_waitcnt vmcnt(0)" ::: "memory");
        __syncthreads();

#pragma unroll
        for (int kk = 0; kk < 2; ++kk) {
            bf16x8 a[4], b[2];
#pragma unroll
            for (int i = 0; i < 4; ++i) {
                const int r  = wm + 16 * i + l15;
                const int sl = (kk * 4 + quad) ^ (r & 7);
                a[i] = *(const bf16x8*)&As[r * 64 + sl * 8];
            }
#pragma unroll
            for (int j = 0; j < 2; ++j) {
                const int r  = wn + 16 * j + l15;
                const int sl = (kk * 4 + quad) ^ (r & 7);
                b[j] = *(const bf16x8*)&Bs[r * 64 + sl * 8];
            }
#pragma unroll
            for (int i = 0; i < 4; ++i)
#pragma unroll
                for (int j = 0; j < 2; ++j)
                    acc[i][j] = mfma16(a[i], b[j], acc[i][j]);
        }
    }

#pragma unroll
    for (int j = 0; j < 2; ++j) {
        const int col = tn + wn + 16 * j + l15;
        const float bj = bias[col];
#pragma unroll
        for (int i = 0; i < 4; ++i) {
            const int row = tm + wm + 16 * i + quad * 4;
#pragma unroll
            for (int r = 0; r < 4; ++r)
                O[(size_t)(row + r) * N + col] = acc[i][j][r] + bj;
        }
    }
}

// ---------------------------------------------------------------------------
// attn8: round-15. T15 double-pipeline on top of attn7:
//  * Iteration kt now runs QK(kt) and PV(kt-1) as adjacent independent MFMA
//    clusters, then exp(kt). P-fragments carried in registers across the
//    iteration boundary (loaded from Pt at end of iter kt-1), so PV has no
//    dependence on this iteration's QK/exp -> MFMA pipe covers exp's VALU
//    run and vice versa.
//  * V triple-buffered (PV reads tile kt-1 while prefetch writes kt+1;
//    (kt-1)%3 != (kt+1)%3 always; top-of-loop barrier orders cross-wave).
//    K stays double-buffered. LDS 49152 -> 57344 (still 2 blocks/CU,
//    grid-limited anyway).
//  * Epilogue does the final PV(KH) (H-only: KH >= 16 > KL always).
// ---------------------------------------------------------------------------
__device__ __forceinline__ bf16x8 rdt(const u16* base, int t, int l15, int cc) {
    const int r = t * 16 + l15;
    const int c = (cc & 3) ^ ((r >> 1) & 3);
    return *(const bf16x8*)(base + (cc >> 2) * 2048 + r * 32 + c * 8);
}

#define QK_EXP(Z, PROW, QG, MASKED, RSV, KB)                                   \
    do {                                                                       \
        _Pragma("unroll")                                                      \
        for (int t = 0; t < 4; ++t) {                                          \
            float e0 = fexp2(fmaf((Z)[t][0], SC, -16.0f));                     \
            float e1 = fexp2(fmaf((Z)[t][1], SC, -16.0f));                     \
            float e2 = fexp2(fmaf((Z)[t][2], SC, -16.0f));                     \
            float e3 = fexp2(fmaf((Z)[t][3], SC, -16.0f));                     \
            if (MASKED) {                                                      \
                const int kb = (KB) + t * 16 + quad * 4;                       \
                if (kb + 0 > (QG)) e0 = 0.f;                                   \
                if (kb + 1 > (QG)) e1 = 0.f;                                   \
                if (kb + 2 > (QG)) e2 = 0.f;                                   \
                if (kb + 3 > (QG)) e3 = 0.f;                                   \
            }                                                                  \
            (RSV)[0] += e0; (RSV)[1] += e1;                                    \
            (RSV)[2] += e2; (RSV)[3] += e3;                                    \
            *(ushort4*)((PROW) + (((2 * t + whi) ^ sl7) << 3) + woff) =        \
                pk4(e0, e1, e2, e3);                                           \
        }                                                                      \
    } while (0)

__global__ __launch_bounds__(256) void attn8(
    const u16* __restrict__ Q, const u16* __restrict__ Kb,
    const u16* __restrict__ VT, u16* __restrict__ ctx)
{
    __shared__ __attribute__((aligned(16))) u16 Kt[2][4096];
    __shared__ __attribute__((aligned(16))) u16 Vt[3][4096];
    __shared__ __attribute__((aligned(16))) u16 Pt[4][32][64];

    const int tid  = threadIdx.x;
    const int lane = tid & 63;
    const int wid  = tid >> 6;
    const int l15  = lane & 15;
    const int quad = lane >> 4;
    const int sl7  = l15 & 7;
    const int whi  = quad >> 1;
    const int woff = (quad & 1) * 4;

    const int hb = blockIdx.x & 31;
    const int h  = hb & 15, b = hb >> 4;
    const int ti = blockIdx.x >> 5;
    const int g  = (ti & 1) ? (15 - (ti >> 1)) : (ti >> 1);

    const int sL = 4 * g + wid, sH = 127 - sL;
    const int KL = g, KH = 31 - g;

    const size_t rowbase = (size_t)b * 2048;
    const int cbase = h * 64;
    const u16* kbase = Kb + rowbase * 1024 + cbase;
    const u16* vbase = VT + ((size_t)b * 1024 + cbase) * 2048;

    const int qgL = sL * 16 + l15, qgH = sH * 16 + l15;
    const u16* qpL = Q + (rowbase + qgL) * 1024 + cbase + quad * 8;
    const u16* qpH = Q + (rowbase + qgH) * 1024 + cbase + quad * 8;
    const bf16x8 qL0 = *(const bf16x8*)qpL, qL1 = *(const bf16x8*)(qpL + 32);
    const bf16x8 qH0 = *(const bf16x8*)qpH, qH1 = *(const bf16x8*)(qpH + 32);

    // staging: row sr = tid>>2, dest chunk tid&3 (linear); source chunk
    // permuted (c ^ ((sr>>1)&3)) so rdt's 16-lane read phases are 2-way.
    const int sr  = tid >> 2;
    const int sc0 = (((tid & 3) ^ ((sr >> 1) & 3)) << 3);
    const u16* kg = kbase + (size_t)sr * 1024 + sc0;
    const u16* vg = vbase + (size_t)sr * 2048 + sc0;

    f32x4 oL[4], oH[4];
#pragma unroll
    for (int i = 0; i < 4; ++i) { oL[i] = f32x4{0,0,0,0}; oH[i] = f32x4{0,0,0,0}; }
    f32x4 rsLv = {0,0,0,0}, rsHv = {0,0,0,0};
    const float SC = 0.18033688011112042f;

    u16 (*ptw)[64] = Pt[wid];
    u16* const prH = &ptw[16 + l15][0];
    u16* const prL = &ptw[l15][0];

    async16(kg,      &Kt[0][tid * 8]);
    async16(kg + 32, &Kt[0][2048 + tid * 8]);
    async16(vg,      &Vt[0][tid * 8]);
    async16(vg + 32, &Vt[0][2048 + tid * 8]);

    // P-fragments carried across iterations (PV of tile kt runs in iter kt+1)
    bf16x8 pbH0 = {}, pbH1 = {}, pbL0 = {}, pbL1 = {};
    bool doLp = false;
    int c3 = 0;  // kt % 3 (V slot of current tile)

    for (int kt = 0; kt <= KH; ++kt) {
        const int curK = kt & 1, nxtK = curK ^ 1;
        const int n3 = (c3 == 2) ? 0 : c3 + 1;   // (kt+1)%3
        const int p3 = 3 - c3 - n3;              // (kt-1)%3 (kt>0)
        asm volatile("s_waitcnt vmcnt(0)" ::: "memory");
        __syncthreads();
        if (kt < KH) {
            const u16* kgn = kg + (size_t)(kt + 1) * 65536;
            const u16* vgn = vg + (kt + 1) * 64;
            async16(kgn,      &Kt[nxtK][tid * 8]);
            async16(kgn + 32, &Kt[nxtK][2048 + tid * 8]);
            async16(vgn,      &Vt[n3][tid * 8]);
            async16(vgn + 32, &Vt[n3][2048 + tid * 8]);
        }
        const u16* KT = Kt[curK];
        const bool doL = (kt <= KL);
        const bool mH = (kt == KH), mL = (kt == KL);

        // ---- QK^T(kt) + PV(kt-1): adjacent independent MFMA clusters ----
        f32x4 zH[4], zL[4];
        __builtin_amdgcn_s_setprio(1);
        if (doL) {
#pragma unroll
            for (int t = 0; t < 4; ++t) {
                const bf16x8 kA = rdt(KT, t, l15, quad);
                const bf16x8 kB = rdt(KT, t, l15, quad + 4);
                f32x4 zh = {0,0,0,0};
                zh = mfma16(kA, qH0, zh);
                zh = mfma16(kB, qH1, zh);
                zH[t] = zh;
                f32x4 zl = {0,0,0,0};
                zl = mfma16(kA, qL0, zl);
                zl = mfma16(kB, qL1, zl);
                zL[t] = zl;
            }
        } else {
#pragma unroll
            for (int t = 0; t < 4; ++t) {
                const bf16x8 kA = rdt(KT, t, l15, quad);
                const bf16x8 kB = rdt(KT, t, l15, quad + 4);
                f32x4 zh = {0,0,0,0};
                zh = mfma16(kA, qH0, zh);
                zh = mfma16(kB, qH1, zh);
                zH[t] = zh;
            }
        }
        if (kt > 0) {
            const u16* VP = Vt[p3];
            if (doLp) {
#pragma unroll
                for (int t = 0; t < 4; ++t) {
                    const bf16x8 vA = rdt(VP, t, l15, quad);
                    const bf16x8 vB = rdt(VP, t, l15, quad + 4);
                    oH[t] = mfma16(vA, pbH0, oH[t]);
                    oH[t] = mfma16(vB, pbH1, oH[t]);
                    oL[t] = mfma16(vA, pbL0, oL[t]);
                    oL[t] = mfma16(vB, pbL1, oL[t]);
                }
            } else {
#pragma unroll
                for (int t = 0; t < 4; ++t) {
                    const bf16x8 vA = rdt(VP, t, l15, quad);
                    const bf16x8 vB = rdt(VP, t, l15, quad + 4);
                    oH[t] = mfma16(vA, pbH0, oH[t]);
                    oH[t] = mfma16(vB, pbH1, oH[t]);
                }
            }
        }
        __builtin_amdgcn_s_setprio(0);

        // ---- exp + pack into Pt (mask peeled: only diagonal tiles pay) ----
        const int ktb = kt * 64;
        if (mH) QK_EXP(zH, prH, qgH, 1, rsHv, ktb);
        else    QK_EXP(zH, prH, qgH, 0, rsHv, ktb);
        if (doL) {
            if (mL) QK_EXP(zL, prL, qgL, 1, rsLv, ktb);
            else    QK_EXP(zL, prL, qgL, 0, rsLv, ktb);
        }

        // ---- load P-fragments for next iteration's PV ----
        pbH0 = *(const bf16x8*)(prH + ((quad ^ sl7) << 3));
        pbH1 = *(const bf16x8*)(prH + (((quad | 4) ^ sl7) << 3));
        if (doL) {
            pbL0 = *(const bf16x8*)(prL + ((quad ^ sl7) << 3));
            pbL1 = *(const bf16x8*)(prL + (((quad | 4) ^ sl7) << 3));
        }
        doLp = doL;
        c3 = n3;
    }

    // ---- epilogue: PV(KH), H-only (KH >= 16 > KL) ----
    {
        const int epi3 = (c3 == 0) ? 2 : c3 - 1;  // KH % 3
        const u16* VP = Vt[epi3];
        __builtin_amdgcn_s_setprio(1);
#pragma unroll
        for (int t = 0; t < 4; ++t) {
            const bf16x8 vA = rdt(VP, t, l15, quad);
            const bf16x8 vB = rdt(VP, t, l15, quad + 4);
            oH[t] = mfma16(vA, pbH0, oH[t]);
            oH[t] = mfma16(vB, pbH1, oH[t]);
        }
        __builtin_amdgcn_s_setprio(0);
    }

    float rsH = (rsHv[0] + rsHv[1]) + (rsHv[2] + rsHv[3]);
    float rsL = (rsLv[0] + rsLv[1]) + (rsLv[2] + rsLv[3]);
    rsH += __shfl_xor(rsH, 16); rsH += __shfl_xor(rsH, 32);
    rsL += __shfl_xor(rsL, 16); rsL += __shfl_xor(rsL, 32);
    const float iH = 1.0f / rsH, iL = 1.0f / rsL;
#pragma unroll
    for (int t = 0; t < 4; ++t) {
        *(ushort4*)&ctx[(rowbase + qgL) * 1024 + cbase + t * 16 + quad * 4] =
            pk4(oL[t][0] * iL, oL[t][1] * iL, oL[t][2] * iL, oL[t][3] * iL);
        *(ushort4*)&ctx[(rowbase + qgH) * 1024 + cbase + t * 16 + quad * 4] =
            pk4(oH[t][0] * iH, oH[t][1] * iH, oH[t][2] * iH, oH[t][3] * iH);
    }
}

extern "C" void kernel_launch(void* const* d_in, const int* in_sizes, int n_in,
                              void* d_out, int out_size, void* d_ws, size_t ws_size,
                              hipStream_t stream) {
    const float* x  = (const float*)d_in[0];
    const float* Wq = (const float*)d_in[1];
    const float* bq = (const float*)d_in[2];
    const float* Wk = (const float*)d_in[3];
    const float* bk = (const float*)d_in[4];
    const float* Wv = (const float*)d_in[5];
    const float* bv = (const float*)d_in[6];
    const float* Wo = (const float*)d_in[7];
    const float* bo = (const float*)d_in[8];
    float* out = (float*)d_out;

    const int N = 1024, K = 1024;
    const int M = in_sizes[0] / K;           // 4096
    const size_t MN = (size_t)M * N;
    const size_t WN = (size_t)N * K;

    u16* xb  = (u16*)d_ws;
    u16* wqb = xb  + MN;
    u16* wkb = wqb + WN;
    u16* wvb = wkb + WN;
    u16* wob = wvb + WN;
    u16* q   = wob + WN;
    u16* kb  = q   + MN;
    u16* vt  = kb  + MN;                     // V^T: [b*1024 + h*64 + d][s]
    u16* ctx = q;                            // alias: disjoint per-wave strips

    cast_all<<<dim3(1024, 5), 256, 0, stream>>>(
        x, Wq, Wk, Wv, Wo, xb, wqb, wkb, wvb, wob);

    gemm_qkv<<<dim3(768), 256, 0, stream>>>(
        xb, wqb, wkb, wvb, bq, bk, bv, q, kb, vt, M, N, K);

    attn8<<<dim3(512), 256, 0, stream>>>(q, kb, vt, ctx);

    gemm_out64<<<dim3(512), 256, 0, stream>>>(
        ctx, wob, bo, out, M, N, K);
}

// Round 3
// 188.360 us; speedup vs baseline: 1.0732x; 1.0236x over previous
//
#include <hip/hip_runtime.h>
#include <stdint.h>

typedef unsigned short u16;
typedef __bf16 bf16x8 __attribute__((ext_vector_type(8)));
typedef __bf16 bf16x4v __attribute__((ext_vector_type(4)));
typedef float f32x4 __attribute__((ext_vector_type(4)));

typedef __attribute__((address_space(3))) uint32_t lds_u32;
typedef __attribute__((address_space(1))) uint32_t glb_u32;

__device__ __forceinline__ f32x4 mfma16(bf16x8 a, bf16x8 b, f32x4 c) {
    return __builtin_amdgcn_mfma_f32_16x16x32_bf16(a, b, c, 0, 0, 0);
}

// 4x f32 -> bf16 via native cvt (RNE), reinterpreted as ushort4
__device__ __forceinline__ ushort4 pk4(float a, float b, float c, float d) {
    bf16x4v v;
    v[0] = (__bf16)a; v[1] = (__bf16)b; v[2] = (__bf16)c; v[3] = (__bf16)d;
    union { bf16x4v v; ushort4 u; } cv; cv.v = v; return cv.u;
}

// raw v_exp_f32 (skip ocml wrapper)
__device__ __forceinline__ float fexp2(float x) {
    return __builtin_amdgcn_exp2f(x);
}

// async global->LDS, 16B per lane (LDS dest = wave base + lane*16)
__device__ __forceinline__ void async16(const u16* g, u16* l) {
    __builtin_amdgcn_global_load_lds((glb_u32*)(uintptr_t)(const void*)g,
                                     (lds_u32*)l, 16, 0, 0);
}

// ---------------------------------------------------------------------------
// fp32 -> bf16 casts (unchanged)
// ---------------------------------------------------------------------------
__global__ __launch_bounds__(256) void cast_all(
    const float* __restrict__ x,
    const float* __restrict__ w0, const float* __restrict__ w1,
    const float* __restrict__ w2, const float* __restrict__ w3,
    u16* __restrict__ xo, u16* __restrict__ o0, u16* __restrict__ o1,
    u16* __restrict__ o2, u16* __restrict__ o3)
{
    const int s = blockIdx.y;
    const int i = (blockIdx.x * 256 + threadIdx.x) * 4;
    if (s == 0) {
#pragma unroll
        for (int c = 0; c < 4; ++c) {
            const int j = i + c * (1 << 20);
            float4 v = *(const float4*)(x + j);
            *(ushort4*)(xo + j) = pk4(v.x, v.y, v.z, v.w);
        }
    } else {
        const float* in = s == 1 ? w0 : (s == 2 ? w1 : (s == 3 ? w2 : w3));
        u16* out       = s == 1 ? o0 : (s == 2 ? o1 : (s == 3 ? o2 : o3));
        float4 v = *(const float4*)(in + i);
        *(ushort4*)(out + i) = pk4(v.x, v.y, v.z, v.w);
    }
}

// ---------------------------------------------------------------------------
// QKV GEMM, round 16: LDS double-buffer + prefetch order (T3 minimum 2-phase).
// Old loop was single-buffered: stage(t) -> vmcnt(0) -> compute(t), putting
// the full staging latency serially in every K-step (MfmaUtil 20%). New loop
// issues STAGE(t+1) before compute(t); the one vmcnt(0)+barrier per tile sits
// AFTER a full compute phase, so load latency hides under 32 MFMAs.
// LDS 32->64 KiB (2 blocks/CU). One barrier per K-step instead of two.
// ---------------------------------------------------------------------------
__global__ __launch_bounds__(256) void gemm_qkv(
    const u16* __restrict__ A,
    const u16* __restrict__ W0, const u16* __restrict__ W1, const u16* __restrict__ W2,
    const float* __restrict__ B0, const float* __restrict__ B1, const float* __restrict__ B2,
    u16* __restrict__ O0, u16* __restrict__ O1,
    u16* __restrict__ VT,
    int M, int N, int K)
{
    const int x = blockIdx.x & 7;
    const int L = blockIdx.x >> 3;                 // 0..95
    const int tm = (8 * (x >> 1) + (L & 7)) << 7;  // 32 tm tiles
    const int tnsel = 12 * (x & 1) + (L >> 3);     // 0..23
    const int sel = tnsel >> 3;
    const int tn  = (tnsel & 7) << 7;

    const u16* W      = sel == 0 ? W0 : (sel == 1 ? W1 : W2);
    const float* bias = sel == 0 ? B0 : (sel == 1 ? B1 : B2);
    u16* O            = sel == 0 ? O0 : O1;        // sel==2 -> VT path

    __shared__ __attribute__((aligned(16))) u16 As[2][128 * 64];
    __shared__ __attribute__((aligned(16))) u16 Bs[2][128 * 64];
    u16 (*Tb)[136] = (u16 (*)[136])As;             // union: post-K-loop only

    const int tid  = threadIdx.x;
    const int lane = tid & 63;
    const int w    = tid >> 6;
    const int l15  = lane & 15;
    const int quad = lane >> 4;

    const int wm = (w >> 1) << 6;
    const int wn = (w & 1) << 6;

    f32x4 acc[4][4];
#pragma unroll
    for (int i = 0; i < 4; ++i)
#pragma unroll
        for (int j = 0; j < 4; ++j) acc[i][j] = f32x4{0.f, 0.f, 0.f, 0.f};

    const int lr  = lane >> 3;                     // 0..7
    const int lcc = lane & 7;                      // dest chunk
    const int scc = lcc ^ lr;                      // source chunk (row&7 == lr)
    const u16* Ag = A + (size_t)(tm + 32 * w + lr) * K + scc * 8;
    const u16* Wg = W + (size_t)(tn + 32 * w + lr) * K + scc * 8;
    u16* Al = &As[0][(32 * w + lr) * 64 + lcc * 8];
    u16* Bl = &Bs[0][(32 * w + lr) * 64 + lcc * 8];

#define QKV_STAGE(bi, k0)                                                      \
    do {                                                                       \
        _Pragma("unroll")                                                      \
        for (int m = 0; m < 4; ++m) {                                          \
            async16(Ag + (k0) + (size_t)m * 8 * K, Al + (bi) * 8192 + m * 512);\
            async16(Wg + (k0) + (size_t)m * 8 * K, Bl + (bi) * 8192 + m * 512);\
        }                                                                      \
    } while (0)

    const int nt = K >> 6;                         // 16
    QKV_STAGE(0, 0);
    for (int t = 0; t < nt; ++t) {
        const int cur = t & 1;
        asm volatile("s_waitcnt vmcnt(0)" ::: "memory");
        __syncthreads();
        if (t + 1 < nt) QKV_STAGE(cur ^ 1, (t + 1) * 64);
        const u16* Ab = As[cur];
        const u16* Bb = Bs[cur];
#pragma unroll
        for (int kk = 0; kk < 2; ++kk) {
            bf16x8 a[4], b[4];
#pragma unroll
            for (int i = 0; i < 4; ++i) {
                const int r  = wm + 16 * i + l15;
                const int sl = (kk * 4 + quad) ^ (r & 7);
                a[i] = *(const bf16x8*)&Ab[r * 64 + sl * 8];
            }
#pragma unroll
            for (int j = 0; j < 4; ++j) {
                const int r  = wn + 16 * j + l15;
                const int sl = (kk * 4 + quad) ^ (r & 7);
                b[j] = *(const bf16x8*)&Bb[r * 64 + sl * 8];
            }
#pragma unroll
            for (int i = 0; i < 4; ++i)
#pragma unroll
                for (int j = 0; j < 4; ++j)
                    acc[i][j] = mfma16(a[i], b[j], acc[i][j]);
        }
    }
#undef QKV_STAGE

    if (sel == 2) {
        const int bb = tm >> 11;
        const int s0 = tm & 2047;
        const size_t vtb = ((size_t)bb << 10) + tn;
        for (int c32 = 0; c32 < 128; c32 += 32) {
            __syncthreads();
            if ((c32 >> 6) == (wn >> 6)) {
                const int j0 = (c32 >> 4) & 2;
#pragma unroll
                for (int jj = 0; jj < 2; ++jj) {
                    const int j  = j0 + jj;
                    const int cc = jj * 16 + l15;
                    const float bj = bias[tn + wn + 16 * j + l15];
#pragma unroll
                    for (int i = 0; i < 4; ++i) {
                        const int rr = wm + 16 * i + quad * 4;
                        *(ushort4*)&Tb[cc][rr] =
                            pk4(acc[i][j][0] + bj, acc[i][j][1] + bj,
                                acc[i][j][2] + bj, acc[i][j][3] + bj);
                    }
                }
            }
            __syncthreads();
            {
                const int c  = tid >> 3;
                const int ss = (tid & 7) * 16;
                uint4 v0 = *(const uint4*)&Tb[c][ss];
                uint4 v1 = *(const uint4*)&Tb[c][ss + 8];
                u16* dst = &VT[(vtb + c32 + c) * 2048 + s0 + ss];
                *(uint4*)dst       = v0;
                *(uint4*)(dst + 8) = v1;
            }
        }
    } else {
#pragma unroll
        for (int j = 0; j < 4; ++j) {
            const int col = tn + wn + 16 * j + l15;
            const float bj = bias[col];
#pragma unroll
            for (int i = 0; i < 4; ++i) {
                const int row = tm + wm + 16 * i + quad * 4;
#pragma unroll
                for (int r = 0; r < 4; ++r) {
                    union { float f; unsigned u; } v; v.f = acc[i][j][r] + bj;
                    unsigned rn = v.u + 0x7FFFu + ((v.u >> 16) & 1u);
                    O[(size_t)(row + r) * N + col] = (u16)(rn >> 16);
                }
            }
        }
    }
}

// ---------------------------------------------------------------------------
// Output projection GEMM, round 16: same double-buffer + prefetch restructure.
// LDS 24 -> 48 KiB (3 blocks/CU).
// ---------------------------------------------------------------------------
__global__ __launch_bounds__(256) void gemm_out64(
    const u16* __restrict__ A, const u16* __restrict__ W,
    const float* __restrict__ bias, float* __restrict__ O,
    int M, int N, int K)
{
    __shared__ __attribute__((aligned(16))) u16 As[2][128 * 64];
    __shared__ __attribute__((aligned(16))) u16 Bs[2][64 * 64];

    const int x = blockIdx.x & 7;
    const int L = blockIdx.x >> 3;                 // 0..63
    const int tm = (8 * (x >> 1) + (L & 7)) << 7;  // 32 tiles
    const int tn = (8 * (x & 1) + (L >> 3)) << 6;  // 16 tiles

    const int tid  = threadIdx.x;
    const int lane = tid & 63;
    const int w    = tid >> 6;
    const int l15  = lane & 15;
    const int quad = lane >> 4;

    const int wm = (w >> 1) << 6;
    const int wn = (w & 1) << 5;

    f32x4 acc[4][2];
#pragma unroll
    for (int i = 0; i < 4; ++i)
#pragma unroll
        for (int j = 0; j < 2; ++j) acc[i][j] = f32x4{0.f, 0.f, 0.f, 0.f};

    const int lr  = lane >> 3;
    const int lcc = lane & 7;
    const int scc = lcc ^ lr;
    const u16* Ag = A + (size_t)(tm + 32 * w + lr) * K + scc * 8;
    const u16* Wg = W + (size_t)(tn + 16 * w + lr) * K + scc * 8;
    u16* Al = &As[0][(32 * w + lr) * 64 + lcc * 8];
    u16* Bl = &Bs[0][(16 * w + lr) * 64 + lcc * 8];

#define OUT_STAGE(bi, k0)                                                      \
    do {                                                                       \
        _Pragma("unroll")                                                      \
        for (int m = 0; m < 4; ++m)                                            \
            async16(Ag + (k0) + (size_t)m * 8 * K, Al + (bi) * 8192 + m * 512);\
        _Pragma("unroll")                                                      \
        for (int m = 0; m < 2; ++m)                                            \
            async16(Wg + (k0) + (size_t)m * 8 * K, Bl + (bi) * 4096 + m * 512);\
    } while (0)

    const int nt = K >> 6;                         // 16
    OUT_STAGE(0, 0);
    for (int t = 0; t < nt; ++t) {
        const int cur = t & 1;
        asm volatile("s_waitcnt vmcnt(0)" ::: "memory");
        __syncthreads();
        if (t + 1 < nt) OUT_STAGE(cur ^ 1, (t + 1) * 64);
        const u16* Ab = As[cur];
        const u16* Bb = Bs[cur];
#pragma unroll
        for (int kk = 0; kk < 2; ++kk) {
            bf16x8 a[4], b[2];
#pragma unroll
            for (int i = 0; i < 4; ++i) {
                const int r  = wm + 16 * i + l15;
                const int sl = (kk * 4 + quad) ^ (r & 7);
                a[i] = *(const bf16x8*)&Ab[r * 64 + sl * 8];
            }
#pragma unroll
            for (int j = 0; j < 2; ++j) {
                const int r  = wn + 16 * j + l15;
                const int sl = (kk * 4 + quad) ^ (r & 7);
                b[j] = *(const bf16x8*)&Bb[r * 64 + sl * 8];
            }
#pragma unroll
            for (int i = 0; i < 4; ++i)
#pragma unroll
                for (int j = 0; j < 2; ++j)
                    acc[i][j] = mfma16(a[i], b[j], acc[i][j]);
        }
    }
#undef OUT_STAGE

#pragma unroll
    for (int j = 0; j < 2; ++j) {
        const int col = tn + wn + 16 * j + l15;
        const float bj = bias[col];
#pragma unroll
        for (int i = 0; i < 4; ++i) {
            const int row = tm + wm + 16 * i + quad * 4;
#pragma unroll
            for (int r = 0; r < 4; ++r)
                O[(size_t)(row + r) * N + col] = acc[i][j][r] + bj;
        }
    }
}

// ---------------------------------------------------------------------------
// attn8 (frozen from round 15)
// ---------------------------------------------------------------------------
__device__ __forceinline__ bf16x8 rdt(const u16* base, int t, int l15, int cc) {
    const int r = t * 16 + l15;
    const int c = (cc & 3) ^ ((r >> 1) & 3);
    return *(const bf16x8*)(base + (cc >> 2) * 2048 + r * 32 + c * 8);
}

#define QK_EXP(Z, PROW, QG, MASKED, RSV, KB)                                   \
    do {                                                                       \
        _Pragma("unroll")                                                      \
        for (int t = 0; t < 4; ++t) {                                          \
            float e0 = fexp2(fmaf((Z)[t][0], SC, -16.0f));                     \
            float e1 = fexp2(fmaf((Z)[t][1], SC, -16.0f));                     \
            float e2 = fexp2(fmaf((Z)[t][2], SC, -16.0f));                     \
            float e3 = fexp2(fmaf((Z)[t][3], SC, -16.0f));                     \
            if (MASKED) {                                                      \
                const int kb = (KB) + t * 16 + quad * 4;                       \
                if (kb + 0 > (QG)) e0 = 0.f;                                   \
                if (kb + 1 > (QG)) e1 = 0.f;                                   \
                if (kb + 2 > (QG)) e2 = 0.f;                                   \
                if (kb + 3 > (QG)) e3 = 0.f;                                   \
            }                                                                  \
            (RSV)[0] += e0; (RSV)[1] += e1;                                    \
            (RSV)[2] += e2; (RSV)[3] += e3;                                    \
            *(ushort4*)((PROW) + (((2 * t + whi) ^ sl7) << 3) + woff) =        \
                pk4(e0, e1, e2, e3);                                           \
        }                                                                      \
    } while (0)

__global__ __launch_bounds__(256) void attn8(
    const u16* __restrict__ Q, const u16* __restrict__ Kb,
    const u16* __restrict__ VT, u16* __restrict__ ctx)
{
    __shared__ __attribute__((aligned(16))) u16 Kt[2][4096];
    __shared__ __attribute__((aligned(16))) u16 Vt[3][4096];
    __shared__ __attribute__((aligned(16))) u16 Pt[4][32][64];

    const int tid  = threadIdx.x;
    const int lane = tid & 63;
    const int wid  = tid >> 6;
    const int l15  = lane & 15;
    const int quad = lane >> 4;
    const int sl7  = l15 & 7;
    const int whi  = quad >> 1;
    const int woff = (quad & 1) * 4;

    const int hb = blockIdx.x & 31;
    const int h  = hb & 15, b = hb >> 4;
    const int ti = blockIdx.x >> 5;
    const int g  = (ti & 1) ? (15 - (ti >> 1)) : (ti >> 1);

    const int sL = 4 * g + wid, sH = 127 - sL;
    const int KL = g, KH = 31 - g;

    const size_t rowbase = (size_t)b * 2048;
    const int cbase = h * 64;
    const u16* kbase = Kb + rowbase * 1024 + cbase;
    const u16* vbase = VT + ((size_t)b * 1024 + cbase) * 2048;

    const int qgL = sL * 16 + l15, qgH = sH * 16 + l15;
    const u16* qpL = Q + (rowbase + qgL) * 1024 + cbase + quad * 8;
    const u16* qpH = Q + (rowbase + qgH) * 1024 + cbase + quad * 8;
    const bf16x8 qL0 = *(const bf16x8*)qpL, qL1 = *(const bf16x8*)(qpL + 32);
    const bf16x8 qH0 = *(const bf16x8*)qpH, qH1 = *(const bf16x8*)(qpH + 32);

    const int sr  = tid >> 2;
    const int sc0 = (((tid & 3) ^ ((sr >> 1) & 3)) << 3);
    const u16* kg = kbase + (size_t)sr * 1024 + sc0;
    const u16* vg = vbase + (size_t)sr * 2048 + sc0;

    f32x4 oL[4], oH[4];
#pragma unroll
    for (int i = 0; i < 4; ++i) { oL[i] = f32x4{0,0,0,0}; oH[i] = f32x4{0,0,0,0}; }
    f32x4 rsLv = {0,0,0,0}, rsHv = {0,0,0,0};
    const float SC = 0.18033688011112042f;

    u16 (*ptw)[64] = Pt[wid];
    u16* const prH = &ptw[16 + l15][0];
    u16* const prL = &ptw[l15][0];

    async16(kg,      &Kt[0][tid * 8]);
    async16(kg + 32, &Kt[0][2048 + tid * 8]);
    async16(vg,      &Vt[0][tid * 8]);
    async16(vg + 32, &Vt[0][2048 + tid * 8]);

    bf16x8 pbH0 = {}, pbH1 = {}, pbL0 = {}, pbL1 = {};
    bool doLp = false;
    int c3 = 0;  // kt % 3 (V slot of current tile)

    for (int kt = 0; kt <= KH; ++kt) {
        const int curK = kt & 1, nxtK = curK ^ 1;
        const int n3 = (c3 == 2) ? 0 : c3 + 1;   // (kt+1)%3
        const int p3 = 3 - c3 - n3;              // (kt-1)%3 (kt>0)
        asm volatile("s_waitcnt vmcnt(0)" ::: "memory");
        __syncthreads();
        if (kt < KH) {
            const u16* kgn = kg + (size_t)(kt + 1) * 65536;
            const u16* vgn = vg + (kt + 1) * 64;
            async16(kgn,      &Kt[nxtK][tid * 8]);
            async16(kgn + 32, &Kt[nxtK][2048 + tid * 8]);
            async16(vgn,      &Vt[n3][tid * 8]);
            async16(vgn + 32, &Vt[n3][2048 + tid * 8]);
        }
        const u16* KT = Kt[curK];
        const bool doL = (kt <= KL);
        const bool mH = (kt == KH), mL = (kt == KL);

        f32x4 zH[4], zL[4];
        __builtin_amdgcn_s_setprio(1);
        if (doL) {
#pragma unroll
            for (int t = 0; t < 4; ++t) {
                const bf16x8 kA = rdt(KT, t, l15, quad);
                const bf16x8 kB = rdt(KT, t, l15, quad + 4);
                f32x4 zh = {0,0,0,0};
                zh = mfma16(kA, qH0, zh);
                zh = mfma16(kB, qH1, zh);
                zH[t] = zh;
                f32x4 zl = {0,0,0,0};
                zl = mfma16(kA, qL0, zl);
                zl = mfma16(kB, qL1, zl);
                zL[t] = zl;
            }
        } else {
#pragma unroll
            for (int t = 0; t < 4; ++t) {
                const bf16x8 kA = rdt(KT, t, l15, quad);
                const bf16x8 kB = rdt(KT, t, l15, quad + 4);
                f32x4 zh = {0,0,0,0};
                zh = mfma16(kA, qH0, zh);
                zh = mfma16(kB, qH1, zh);
                zH[t] = zh;
            }
        }
        if (kt > 0) {
            const u16* VP = Vt[p3];
            if (doLp) {
#pragma unroll
                for (int t = 0; t < 4; ++t) {
                    const bf16x8 vA = rdt(VP, t, l15, quad);
                    const bf16x8 vB = rdt(VP, t, l15, quad + 4);
                    oH[t] = mfma16(vA, pbH0, oH[t]);
                    oH[t] = mfma16(vB, pbH1, oH[t]);
                    oL[t] = mfma16(vA, pbL0, oL[t]);
                    oL[t] = mfma16(vB, pbL1, oL[t]);
                }
            } else {
#pragma unroll
                for (int t = 0; t < 4; ++t) {
                    const bf16x8 vA = rdt(VP, t, l15, quad);
                    const bf16x8 vB = rdt(VP, t, l15, quad + 4);
                    oH[t] = mfma16(vA, pbH0, oH[t]);
                    oH[t] = mfma16(vB, pbH1, oH[t]);
                }
            }
        }
        __builtin_amdgcn_s_setprio(0);

        const int ktb = kt * 64;
        if (mH) QK_EXP(zH, prH, qgH, 1, rsHv, ktb);
        else    QK_EXP(zH, prH, qgH, 0, rsHv, ktb);
        if (doL) {
            if (mL) QK_EXP(zL, prL, qgL, 1, rsLv, ktb);
            else    QK_EXP(zL, prL, qgL, 0, rsLv, ktb);
        }

        pbH0 = *(const bf16x8*)(prH + ((quad ^ sl7) << 3));
        pbH1 = *(const bf16x8*)(prH + (((quad | 4) ^ sl7) << 3));
        if (doL) {
            pbL0 = *(const bf16x8*)(prL + ((quad ^ sl7) << 3));
            pbL1 = *(const bf16x8*)(prL + (((quad | 4) ^ sl7) << 3));
        }
        doLp = doL;
        c3 = n3;
    }

    {
        const int epi3 = (c3 == 0) ? 2 : c3 - 1;  // KH % 3
        const u16* VP = Vt[epi3];
        __builtin_amdgcn_s_setprio(1);
#pragma unroll
        for (int t = 0; t < 4; ++t) {
            const bf16x8 vA = rdt(VP, t, l15, quad);
            const bf16x8 vB = rdt(VP, t, l15, quad + 4);
            oH[t] = mfma16(vA, pbH0, oH[t]);
            oH[t] = mfma16(vB, pbH1, oH[t]);
        }
        __builtin_amdgcn_s_setprio(0);
    }

    float rsH = (rsHv[0] + rsHv[1]) + (rsHv[2] + rsHv[3]);
    float rsL = (rsLv[0] + rsLv[1]) + (rsLv[2] + rsLv[3]);
    rsH += __shfl_xor(rsH, 16); rsH += __shfl_xor(rsH, 32);
    rsL += __shfl_xor(rsL, 16); rsL += __shfl_xor(rsL, 32);
    const float iH = 1.0f / rsH, iL = 1.0f / rsL;
#pragma unroll
    for (int t = 0; t < 4; ++t) {
        *(ushort4*)&ctx[(rowbase + qgL) * 1024 + cbase + t * 16 + quad * 4] =
            pk4(oL[t][0] * iL, oL[t][1] * iL, oL[t][2] * iL, oL[t][3] * iL);
        *(ushort4*)&ctx[(rowbase + qgH) * 1024 + cbase + t * 16 + quad * 4] =
            pk4(oH[t][0] * iH, oH[t][1] * iH, oH[t][2] * iH, oH[t][3] * iH);
    }
}

extern "C" void kernel_launch(void* const* d_in, const int* in_sizes, int n_in,
                              void* d_out, int out_size, void* d_ws, size_t ws_size,
                              hipStream_t stream) {
    const float* x  = (const float*)d_in[0];
    const float* Wq = (const float*)d_in[1];
    const float* bq = (const float*)d_in[2];
    const float* Wk = (const float*)d_in[3];
    const float* bk = (const float*)d_in[4];
    const float* Wv = (const float*)d_in[5];
    const float* bv = (const float*)d_in[6];
    const float* Wo = (const float*)d_in[7];
    const float* bo = (const float*)d_in[8];
    float* out = (float*)d_out;

    const int N = 1024, K = 1024;
    const int M = in_sizes[0] / K;           // 4096
    const size_t MN = (size_t)M * N;
    const size_t WN = (size_t)N * K;

    u16* xb  = (u16*)d_ws;
    u16* wqb = xb  + MN;
    u16* wkb = wqb + WN;
    u16* wvb = wkb + WN;
    u16* wob = wvb + WN;
    u16* q   = wob + WN;
    u16* kb  = q   + MN;
    u16* vt  = kb  + MN;                     // V^T: [b*1024 + h*64 + d][s]
    u16* ctx = q;                            // alias: disjoint per-wave strips

    cast_all<<<dim3(1024, 5), 256, 0, stream>>>(
        x, Wq, Wk, Wv, Wo, xb, wqb, wkb, wvb, wob);

    gemm_qkv<<<dim3(768), 256, 0, stream>>>(
        xb, wqb, wkb, wvb, bq, bk, bv, q, kb, vt, M, N, K);

    attn8<<<dim3(512), 256, 0, stream>>>(q, kb, vt, ctx);

    gemm_out64<<<dim3(512), 256, 0, stream>>>(
        ctx, wob, bo, out, M, N, K);
}

// Round 4
// 186.497 us; speedup vs baseline: 1.0839x; 1.0100x over previous
//
#include <hip/hip_runtime.h>
#include <stdint.h>

typedef unsigned short u16;
typedef __bf16 bf16x8 __attribute__((ext_vector_type(8)));
typedef __bf16 bf16x4v __attribute__((ext_vector_type(4)));
typedef float f32x4 __attribute__((ext_vector_type(4)));

typedef __attribute__((address_space(3))) uint32_t lds_u32;
typedef __attribute__((address_space(1))) uint32_t glb_u32;

__device__ __forceinline__ f32x4 mfma16(bf16x8 a, bf16x8 b, f32x4 c) {
    return __builtin_amdgcn_mfma_f32_16x16x32_bf16(a, b, c, 0, 0, 0);
}

// 4x f32 -> bf16 via native cvt (RNE), reinterpreted as ushort4
__device__ __forceinline__ ushort4 pk4(float a, float b, float c, float d) {
    bf16x4v v;
    v[0] = (__bf16)a; v[1] = (__bf16)b; v[2] = (__bf16)c; v[3] = (__bf16)d;
    union { bf16x4v v; ushort4 u; } cv; cv.v = v; return cv.u;
}

// raw v_exp_f32 (skip ocml wrapper)
__device__ __forceinline__ float fexp2(float x) {
    return __builtin_amdgcn_exp2f(x);
}

// async global->LDS, 16B per lane (LDS dest = wave base + lane*16)
__device__ __forceinline__ void async16(const u16* g, u16* l) {
    __builtin_amdgcn_global_load_lds((glb_u32*)(uintptr_t)(const void*)g,
                                     (lds_u32*)l, 16, 0, 0);
}

// ---------------------------------------------------------------------------
// fp32 -> bf16 casts (unchanged)
// ---------------------------------------------------------------------------
__global__ __launch_bounds__(256) void cast_all(
    const float* __restrict__ x,
    const float* __restrict__ w0, const float* __restrict__ w1,
    const float* __restrict__ w2, const float* __restrict__ w3,
    u16* __restrict__ xo, u16* __restrict__ o0, u16* __restrict__ o1,
    u16* __restrict__ o2, u16* __restrict__ o3)
{
    const int s = blockIdx.y;
    const int i = (blockIdx.x * 256 + threadIdx.x) * 4;
    if (s == 0) {
#pragma unroll
        for (int c = 0; c < 4; ++c) {
            const int j = i + c * (1 << 20);
            float4 v = *(const float4*)(x + j);
            *(ushort4*)(xo + j) = pk4(v.x, v.y, v.z, v.w);
        }
    } else {
        const float* in = s == 1 ? w0 : (s == 2 ? w1 : (s == 3 ? w2 : w3));
        u16* out       = s == 1 ? o0 : (s == 2 ? o1 : (s == 3 ? o2 : o3));
        float4 v = *(const float4*)(in + i);
        *(ushort4*)(out + i) = pk4(v.x, v.y, v.z, v.w);
    }
}

// ---------------------------------------------------------------------------
// QKV GEMM (frozen from round 16: double-buffer + prefetch)
// ---------------------------------------------------------------------------
__global__ __launch_bounds__(256) void gemm_qkv(
    const u16* __restrict__ A,
    const u16* __restrict__ W0, const u16* __restrict__ W1, const u16* __restrict__ W2,
    const float* __restrict__ B0, const float* __restrict__ B1, const float* __restrict__ B2,
    u16* __restrict__ O0, u16* __restrict__ O1,
    u16* __restrict__ VT,
    int M, int N, int K)
{
    const int x = blockIdx.x & 7;
    const int L = blockIdx.x >> 3;                 // 0..95
    const int tm = (8 * (x >> 1) + (L & 7)) << 7;  // 32 tm tiles
    const int tnsel = 12 * (x & 1) + (L >> 3);     // 0..23
    const int sel = tnsel >> 3;
    const int tn  = (tnsel & 7) << 7;

    const u16* W      = sel == 0 ? W0 : (sel == 1 ? W1 : W2);
    const float* bias = sel == 0 ? B0 : (sel == 1 ? B1 : B2);
    u16* O            = sel == 0 ? O0 : O1;        // sel==2 -> VT path

    __shared__ __attribute__((aligned(16))) u16 As[2][128 * 64];
    __shared__ __attribute__((aligned(16))) u16 Bs[2][128 * 64];
    u16 (*Tb)[136] = (u16 (*)[136])As;             // union: post-K-loop only

    const int tid  = threadIdx.x;
    const int lane = tid & 63;
    const int w    = tid >> 6;
    const int l15  = lane & 15;
    const int quad = lane >> 4;

    const int wm = (w >> 1) << 6;
    const int wn = (w & 1) << 6;

    f32x4 acc[4][4];
#pragma unroll
    for (int i = 0; i < 4; ++i)
#pragma unroll
        for (int j = 0; j < 4; ++j) acc[i][j] = f32x4{0.f, 0.f, 0.f, 0.f};

    const int lr  = lane >> 3;                     // 0..7
    const int lcc = lane & 7;                      // dest chunk
    const int scc = lcc ^ lr;                      // source chunk (row&7 == lr)
    const u16* Ag = A + (size_t)(tm + 32 * w + lr) * K + scc * 8;
    const u16* Wg = W + (size_t)(tn + 32 * w + lr) * K + scc * 8;
    u16* Al = &As[0][(32 * w + lr) * 64 + lcc * 8];
    u16* Bl = &Bs[0][(32 * w + lr) * 64 + lcc * 8];

#define QKV_STAGE(bi, k0)                                                      \
    do {                                                                       \
        _Pragma("unroll")                                                      \
        for (int m = 0; m < 4; ++m) {                                          \
            async16(Ag + (k0) + (size_t)m * 8 * K, Al + (bi) * 8192 + m * 512);\
            async16(Wg + (k0) + (size_t)m * 8 * K, Bl + (bi) * 8192 + m * 512);\
        }                                                                      \
    } while (0)

    const int nt = K >> 6;                         // 16
    QKV_STAGE(0, 0);
    for (int t = 0; t < nt; ++t) {
        const int cur = t & 1;
        asm volatile("s_waitcnt vmcnt(0)" ::: "memory");
        __syncthreads();
        if (t + 1 < nt) QKV_STAGE(cur ^ 1, (t + 1) * 64);
        const u16* Ab = As[cur];
        const u16* Bb = Bs[cur];
#pragma unroll
        for (int kk = 0; kk < 2; ++kk) {
            bf16x8 a[4], b[4];
#pragma unroll
            for (int i = 0; i < 4; ++i) {
                const int r  = wm + 16 * i + l15;
                const int sl = (kk * 4 + quad) ^ (r & 7);
                a[i] = *(const bf16x8*)&Ab[r * 64 + sl * 8];
            }
#pragma unroll
            for (int j = 0; j < 4; ++j) {
                const int r  = wn + 16 * j + l15;
                const int sl = (kk * 4 + quad) ^ (r & 7);
                b[j] = *(const bf16x8*)&Bb[r * 64 + sl * 8];
            }
#pragma unroll
            for (int i = 0; i < 4; ++i)
#pragma unroll
                for (int j = 0; j < 4; ++j)
                    acc[i][j] = mfma16(a[i], b[j], acc[i][j]);
        }
    }
#undef QKV_STAGE

    if (sel == 2) {
        const int bb = tm >> 11;
        const int s0 = tm & 2047;
        const size_t vtb = ((size_t)bb << 10) + tn;
        for (int c32 = 0; c32 < 128; c32 += 32) {
            __syncthreads();
            if ((c32 >> 6) == (wn >> 6)) {
                const int j0 = (c32 >> 4) & 2;
#pragma unroll
                for (int jj = 0; jj < 2; ++jj) {
                    const int j  = j0 + jj;
                    const int cc = jj * 16 + l15;
                    const float bj = bias[tn + wn + 16 * j + l15];
#pragma unroll
                    for (int i = 0; i < 4; ++i) {
                        const int rr = wm + 16 * i + quad * 4;
                        *(ushort4*)&Tb[cc][rr] =
                            pk4(acc[i][j][0] + bj, acc[i][j][1] + bj,
                                acc[i][j][2] + bj, acc[i][j][3] + bj);
                    }
                }
            }
            __syncthreads();
            {
                const int c  = tid >> 3;
                const int ss = (tid & 7) * 16;
                uint4 v0 = *(const uint4*)&Tb[c][ss];
                uint4 v1 = *(const uint4*)&Tb[c][ss + 8];
                u16* dst = &VT[(vtb + c32 + c) * 2048 + s0 + ss];
                *(uint4*)dst       = v0;
                *(uint4*)(dst + 8) = v1;
            }
        }
    } else {
#pragma unroll
        for (int j = 0; j < 4; ++j) {
            const int col = tn + wn + 16 * j + l15;
            const float bj = bias[col];
#pragma unroll
            for (int i = 0; i < 4; ++i) {
                const int row = tm + wm + 16 * i + quad * 4;
#pragma unroll
                for (int r = 0; r < 4; ++r) {
                    union { float f; unsigned u; } v; v.f = acc[i][j][r] + bj;
                    unsigned rn = v.u + 0x7FFFu + ((v.u >> 16) & 1u);
                    O[(size_t)(row + r) * N + col] = (u16)(rn >> 16);
                }
            }
        }
    }
}

// ---------------------------------------------------------------------------
// Output projection GEMM (frozen from round 16)
// ---------------------------------------------------------------------------
__global__ __launch_bounds__(256) void gemm_out64(
    const u16* __restrict__ A, const u16* __restrict__ W,
    const float* __restrict__ bias, float* __restrict__ O,
    int M, int N, int K)
{
    __shared__ __attribute__((aligned(16))) u16 As[2][128 * 64];
    __shared__ __attribute__((aligned(16))) u16 Bs[2][64 * 64];

    const int x = blockIdx.x & 7;
    const int L = blockIdx.x >> 3;                 // 0..63
    const int tm = (8 * (x >> 1) + (L & 7)) << 7;  // 32 tiles
    const int tn = (8 * (x & 1) + (L >> 3)) << 6;  // 16 tiles

    const int tid  = threadIdx.x;
    const int lane = tid & 63;
    const int w    = tid >> 6;
    const int l15  = lane & 15;
    const int quad = lane >> 4;

    const int wm = (w >> 1) << 6;
    const int wn = (w & 1) << 5;

    f32x4 acc[4][2];
#pragma unroll
    for (int i = 0; i < 4; ++i)
#pragma unroll
        for (int j = 0; j < 2; ++j) acc[i][j] = f32x4{0.f, 0.f, 0.f, 0.f};

    const int lr  = lane >> 3;
    const int lcc = lane & 7;
    const int scc = lcc ^ lr;
    const u16* Ag = A + (size_t)(tm + 32 * w + lr) * K + scc * 8;
    const u16* Wg = W + (size_t)(tn + 16 * w + lr) * K + scc * 8;
    u16* Al = &As[0][(32 * w + lr) * 64 + lcc * 8];
    u16* Bl = &Bs[0][(16 * w + lr) * 64 + lcc * 8];

#define OUT_STAGE(bi, k0)                                                      \
    do {                                                                       \
        _Pragma("unroll")                                                      \
        for (int m = 0; m < 4; ++m)                                            \
            async16(Ag + (k0) + (size_t)m * 8 * K, Al + (bi) * 8192 + m * 512);\
        _Pragma("unroll")                                                      \
        for (int m = 0; m < 2; ++m)                                            \
            async16(Wg + (k0) + (size_t)m * 8 * K, Bl + (bi) * 4096 + m * 512);\
    } while (0)

    const int nt = K >> 6;                         // 16
    OUT_STAGE(0, 0);
    for (int t = 0; t < nt; ++t) {
        const int cur = t & 1;
        asm volatile("s_waitcnt vmcnt(0)" ::: "memory");
        __syncthreads();
        if (t + 1 < nt) OUT_STAGE(cur ^ 1, (t + 1) * 64);
        const u16* Ab = As[cur];
        const u16* Bb = Bs[cur];
#pragma unroll
        for (int kk = 0; kk < 2; ++kk) {
            bf16x8 a[4], b[2];
#pragma unroll
            for (int i = 0; i < 4; ++i) {
                const int r  = wm + 16 * i + l15;
                const int sl = (kk * 4 + quad) ^ (r & 7);
                a[i] = *(const bf16x8*)&Ab[r * 64 + sl * 8];
            }
#pragma unroll
            for (int j = 0; j < 2; ++j) {
                const int r  = wn + 16 * j + l15;
                const int sl = (kk * 4 + quad) ^ (r & 7);
                b[j] = *(const bf16x8*)&Bb[r * 64 + sl * 8];
            }
#pragma unroll
            for (int i = 0; i < 4; ++i)
#pragma unroll
                for (int j = 0; j < 2; ++j)
                    acc[i][j] = mfma16(a[i], b[j], acc[i][j]);
        }
    }
#undef OUT_STAGE

#pragma unroll
    for (int j = 0; j < 2; ++j) {
        const int col = tn + wn + 16 * j + l15;
        const float bj = bias[col];
#pragma unroll
        for (int i = 0; i < 4; ++i) {
            const int row = tm + wm + 16 * i + quad * 4;
#pragma unroll
            for (int r = 0; r < 4; ++r)
                O[(size_t)(row + r) * N + col] = acc[i][j][r] + bj;
        }
    }
}

// ---------------------------------------------------------------------------
// attn9: round-17. ONLY change vs attn8: the diagonal-group mapping.
// Dispatch model: block i -> XCD i%8, CU slot (i>>3)%32, so CU c co-hosts
// blocks c and c+256, i.e. tiles ti and ti+8. Per-block work = 32-g
// iterations. Old snake (g = ti&1 ? 15-(ti>>1) : ti>>1) gave co-resident
// work sums ranging 38..60 (mean 49) -> tail at half occupancy (measured
// OccupancyPercent 16% vs 25% ceiling). New mapping g = (ti<8) ? ti : 23-ti
// makes every co-resident pair sum to exactly 49.
// ---------------------------------------------------------------------------
__device__ __forceinline__ bf16x8 rdt(const u16* base, int t, int l15, int cc) {
    const int r = t * 16 + l15;
    const int c = (cc & 3) ^ ((r >> 1) & 3);
    return *(const bf16x8*)(base + (cc >> 2) * 2048 + r * 32 + c * 8);
}

#define QK_EXP(Z, PROW, QG, MASKED, RSV, KB)                                   \
    do {                                                                       \
        _Pragma("unroll")                                                      \
        for (int t = 0; t < 4; ++t) {                                          \
            float e0 = fexp2(fmaf((Z)[t][0], SC, -16.0f));                     \
            float e1 = fexp2(fmaf((Z)[t][1], SC, -16.0f));                     \
            float e2 = fexp2(fmaf((Z)[t][2], SC, -16.0f));                     \
            float e3 = fexp2(fmaf((Z)[t][3], SC, -16.0f));                     \
            if (MASKED) {                                                      \
                const int kb = (KB) + t * 16 + quad * 4;                       \
                if (kb + 0 > (QG)) e0 = 0.f;                                   \
                if (kb + 1 > (QG)) e1 = 0.f;                                   \
                if (kb + 2 > (QG)) e2 = 0.f;                                   \
                if (kb + 3 > (QG)) e3 = 0.f;                                   \
            }                                                                  \
            (RSV)[0] += e0; (RSV)[1] += e1;                                    \
            (RSV)[2] += e2; (RSV)[3] += e3;                                    \
            *(ushort4*)((PROW) + (((2 * t + whi) ^ sl7) << 3) + woff) =        \
                pk4(e0, e1, e2, e3);                                           \
        }                                                                      \
    } while (0)

__global__ __launch_bounds__(256) void attn9(
    const u16* __restrict__ Q, const u16* __restrict__ Kb,
    const u16* __restrict__ VT, u16* __restrict__ ctx)
{
    __shared__ __attribute__((aligned(16))) u16 Kt[2][4096];
    __shared__ __attribute__((aligned(16))) u16 Vt[3][4096];
    __shared__ __attribute__((aligned(16))) u16 Pt[4][32][64];

    const int tid  = threadIdx.x;
    const int lane = tid & 63;
    const int wid  = tid >> 6;
    const int l15  = lane & 15;
    const int quad = lane >> 4;
    const int sl7  = l15 & 7;
    const int whi  = quad >> 1;
    const int woff = (quad & 1) * 4;

    const int hb = blockIdx.x & 31;
    const int h  = hb & 15, b = hb >> 4;
    const int ti = blockIdx.x >> 5;
    const int g  = (ti < 8) ? ti : 23 - ti;   // co-resident pairs (ti,ti+8) sum to 49

    const int sL = 4 * g + wid, sH = 127 - sL;
    const int KL = g, KH = 31 - g;

    const size_t rowbase = (size_t)b * 2048;
    const int cbase = h * 64;
    const u16* kbase = Kb + rowbase * 1024 + cbase;
    const u16* vbase = VT + ((size_t)b * 1024 + cbase) * 2048;

    const int qgL = sL * 16 + l15, qgH = sH * 16 + l15;
    const u16* qpL = Q + (rowbase + qgL) * 1024 + cbase + quad * 8;
    const u16* qpH = Q + (rowbase + qgH) * 1024 + cbase + quad * 8;
    const bf16x8 qL0 = *(const bf16x8*)qpL, qL1 = *(const bf16x8*)(qpL + 32);
    const bf16x8 qH0 = *(const bf16x8*)qpH, qH1 = *(const bf16x8*)(qpH + 32);

    const int sr  = tid >> 2;
    const int sc0 = (((tid & 3) ^ ((sr >> 1) & 3)) << 3);
    const u16* kg = kbase + (size_t)sr * 1024 + sc0;
    const u16* vg = vbase + (size_t)sr * 2048 + sc0;

    f32x4 oL[4], oH[4];
#pragma unroll
    for (int i = 0; i < 4; ++i) { oL[i] = f32x4{0,0,0,0}; oH[i] = f32x4{0,0,0,0}; }
    f32x4 rsLv = {0,0,0,0}, rsHv = {0,0,0,0};
    const float SC = 0.18033688011112042f;

    u16 (*ptw)[64] = Pt[wid];
    u16* const prH = &ptw[16 + l15][0];
    u16* const prL = &ptw[l15][0];

    async16(kg,      &Kt[0][tid * 8]);
    async16(kg + 32, &Kt[0][2048 + tid * 8]);
    async16(vg,      &Vt[0][tid * 8]);
    async16(vg + 32, &Vt[0][2048 + tid * 8]);

    bf16x8 pbH0 = {}, pbH1 = {}, pbL0 = {}, pbL1 = {};
    bool doLp = false;
    int c3 = 0;  // kt % 3 (V slot of current tile)

    for (int kt = 0; kt <= KH; ++kt) {
        const int curK = kt & 1, nxtK = curK ^ 1;
        const int n3 = (c3 == 2) ? 0 : c3 + 1;   // (kt+1)%3
        const int p3 = 3 - c3 - n3;              // (kt-1)%3 (kt>0)
        asm volatile("s_waitcnt vmcnt(0)" ::: "memory");
        __syncthreads();
        if (kt < KH) {
            const u16* kgn = kg + (size_t)(kt + 1) * 65536;
            const u16* vgn = vg + (kt + 1) * 64;
            async16(kgn,      &Kt[nxtK][tid * 8]);
            async16(kgn + 32, &Kt[nxtK][2048 + tid * 8]);
            async16(vgn,      &Vt[n3][tid * 8]);
            async16(vgn + 32, &Vt[n3][2048 + tid * 8]);
        }
        const u16* KT = Kt[curK];
        const bool doL = (kt <= KL);
        const bool mH = (kt == KH), mL = (kt == KL);

        f32x4 zH[4], zL[4];
        __builtin_amdgcn_s_setprio(1);
        if (doL) {
#pragma unroll
            for (int t = 0; t < 4; ++t) {
                const bf16x8 kA = rdt(KT, t, l15, quad);
                const bf16x8 kB = rdt(KT, t, l15, quad + 4);
                f32x4 zh = {0,0,0,0};
                zh = mfma16(kA, qH0, zh);
                zh = mfma16(kB, qH1, zh);
                zH[t] = zh;
                f32x4 zl = {0,0,0,0};
                zl = mfma16(kA, qL0, zl);
                zl = mfma16(kB, qL1, zl);
                zL[t] = zl;
            }
        } else {
#pragma unroll
            for (int t = 0; t < 4; ++t) {
                const bf16x8 kA = rdt(KT, t, l15, quad);
                const bf16x8 kB = rdt(KT, t, l15, quad + 4);
                f32x4 zh = {0,0,0,0};
                zh = mfma16(kA, qH0, zh);
                zh = mfma16(kB, qH1, zh);
                zH[t] = zh;
            }
        }
        if (kt > 0) {
            const u16* VP = Vt[p3];
            if (doLp) {
#pragma unroll
                for (int t = 0; t < 4; ++t) {
                    const bf16x8 vA = rdt(VP, t, l15, quad);
                    const bf16x8 vB = rdt(VP, t, l15, quad + 4);
                    oH[t] = mfma16(vA, pbH0, oH[t]);
                    oH[t] = mfma16(vB, pbH1, oH[t]);
                    oL[t] = mfma16(vA, pbL0, oL[t]);
                    oL[t] = mfma16(vB, pbL1, oL[t]);
                }
            } else {
#pragma unroll
                for (int t = 0; t < 4; ++t) {
                    const bf16x8 vA = rdt(VP, t, l15, quad);
                    const bf16x8 vB = rdt(VP, t, l15, quad + 4);
                    oH[t] = mfma16(vA, pbH0, oH[t]);
                    oH[t] = mfma16(vB, pbH1, oH[t]);
                }
            }
        }
        __builtin_amdgcn_s_setprio(0);

        const int ktb = kt * 64;
        if (mH) QK_EXP(zH, prH, qgH, 1, rsHv, ktb);
        else    QK_EXP(zH, prH, qgH, 0, rsHv, ktb);
        if (doL) {
            if (mL) QK_EXP(zL, prL, qgL, 1, rsLv, ktb);
            else    QK_EXP(zL, prL, qgL, 0, rsLv, ktb);
        }

        pbH0 = *(const bf16x8*)(prH + ((quad ^ sl7) << 3));
        pbH1 = *(const bf16x8*)(prH + (((quad | 4) ^ sl7) << 3));
        if (doL) {
            pbL0 = *(const bf16x8*)(prL + ((quad ^ sl7) << 3));
            pbL1 = *(const bf16x8*)(prL + (((quad | 4) ^ sl7) << 3));
        }
        doLp = doL;
        c3 = n3;
    }

    {
        const int epi3 = (c3 == 0) ? 2 : c3 - 1;  // KH % 3
        const u16* VP = Vt[epi3];
        __builtin_amdgcn_s_setprio(1);
#pragma unroll
        for (int t = 0; t < 4; ++t) {
            const bf16x8 vA = rdt(VP, t, l15, quad);
            const bf16x8 vB = rdt(VP, t, l15, quad + 4);
            oH[t] = mfma16(vA, pbH0, oH[t]);
            oH[t] = mfma16(vB, pbH1, oH[t]);
        }
        __builtin_amdgcn_s_setprio(0);
    }

    float rsH = (rsHv[0] + rsHv[1]) + (rsHv[2] + rsHv[3]);
    float rsL = (rsLv[0] + rsLv[1]) + (rsLv[2] + rsLv[3]);
    rsH += __shfl_xor(rsH, 16); rsH += __shfl_xor(rsH, 32);
    rsL += __shfl_xor(rsL, 16); rsL += __shfl_xor(rsL, 32);
    const float iH = 1.0f / rsH, iL = 1.0f / rsL;
#pragma unroll
    for (int t = 0; t < 4; ++t) {
        *(ushort4*)&ctx[(rowbase + qgL) * 1024 + cbase + t * 16 + quad * 4] =
            pk4(oL[t][0] * iL, oL[t][1] * iL, oL[t][2] * iL, oL[t][3] * iL);
        *(ushort4*)&ctx[(rowbase + qgH) * 1024 + cbase + t * 16 + quad * 4] =
            pk4(oH[t][0] * iH, oH[t][1] * iH, oH[t][2] * iH, oH[t][3] * iH);
    }
}

extern "C" void kernel_launch(void* const* d_in, const int* in_sizes, int n_in,
                              void* d_out, int out_size, void* d_ws, size_t ws_size,
                              hipStream_t stream) {
    const float* x  = (const float*)d_in[0];
    const float* Wq = (const float*)d_in[1];
    const float* bq = (const float*)d_in[2];
    const float* Wk = (const float*)d_in[3];
    const float* bk = (const float*)d_in[4];
    const float* Wv = (const float*)d_in[5];
    const float* bv = (const float*)d_in[6];
    const float* Wo = (const float*)d_in[7];
    const float* bo = (const float*)d_in[8];
    float* out = (float*)d_out;

    const int N = 1024, K = 1024;
    const int M = in_sizes[0] / K;           // 4096
    const size_t MN = (size_t)M * N;
    const size_t WN = (size_t)N * K;

    u16* xb  = (u16*)d_ws;
    u16* wqb = xb  + MN;
    u16* wkb = wqb + WN;
    u16* wvb = wkb + WN;
    u16* wob = wvb + WN;
    u16* q   = wob + WN;
    u16* kb  = q   + MN;
    u16* vt  = kb  + MN;                     // V^T: [b*1024 + h*64 + d][s]
    u16* ctx = q;                            // alias: disjoint per-wave strips

    cast_all<<<dim3(1024, 5), 256, 0, stream>>>(
        x, Wq, Wk, Wv, Wo, xb, wqb, wkb, wvb, wob);

    gemm_qkv<<<dim3(768), 256, 0, stream>>>(
        xb, wqb, wkb, wvb, bq, bk, bv, q, kb, vt, M, N, K);

    attn9<<<dim3(512), 256, 0, stream>>>(q, kb, vt, ctx);

    gemm_out64<<<dim3(512), 256, 0, stream>>>(
        ctx, wob, bo, out, M, N, K);
}

// Round 5
// 184.703 us; speedup vs baseline: 1.0944x; 1.0097x over previous
//
#include <hip/hip_runtime.h>
#include <stdint.h>

typedef unsigned short u16;
typedef __bf16 bf16x8 __attribute__((ext_vector_type(8)));
typedef __bf16 bf16x4v __attribute__((ext_vector_type(4)));
typedef float f32x4 __attribute__((ext_vector_type(4)));

typedef __attribute__((address_space(3))) uint32_t lds_u32;
typedef __attribute__((address_space(1))) uint32_t glb_u32;

__device__ __forceinline__ f32x4 mfma16(bf16x8 a, bf16x8 b, f32x4 c) {
    return __builtin_amdgcn_mfma_f32_16x16x32_bf16(a, b, c, 0, 0, 0);
}

// 4x f32 -> bf16 via native cvt (RNE), reinterpreted as ushort4
__device__ __forceinline__ ushort4 pk4(float a, float b, float c, float d) {
    bf16x4v v;
    v[0] = (__bf16)a; v[1] = (__bf16)b; v[2] = (__bf16)c; v[3] = (__bf16)d;
    union { bf16x4v v; ushort4 u; } cv; cv.v = v; return cv.u;
}

// raw v_exp_f32 (skip ocml wrapper)
__device__ __forceinline__ float fexp2(float x) {
    return __builtin_amdgcn_exp2f(x);
}

// async global->LDS, 16B per lane (LDS dest = wave base + lane*16)
__device__ __forceinline__ void async16(const u16* g, u16* l) {
    __builtin_amdgcn_global_load_lds((glb_u32*)(uintptr_t)(const void*)g,
                                     (lds_u32*)l, 16, 0, 0);
}

// ---------------------------------------------------------------------------
// fp32 -> bf16 casts (unchanged)
// ---------------------------------------------------------------------------
__global__ __launch_bounds__(256) void cast_all(
    const float* __restrict__ x,
    const float* __restrict__ w0, const float* __restrict__ w1,
    const float* __restrict__ w2, const float* __restrict__ w3,
    u16* __restrict__ xo, u16* __restrict__ o0, u16* __restrict__ o1,
    u16* __restrict__ o2, u16* __restrict__ o3)
{
    const int s = blockIdx.y;
    const int i = (blockIdx.x * 256 + threadIdx.x) * 4;
    if (s == 0) {
#pragma unroll
        for (int c = 0; c < 4; ++c) {
            const int j = i + c * (1 << 20);
            float4 v = *(const float4*)(x + j);
            *(ushort4*)(xo + j) = pk4(v.x, v.y, v.z, v.w);
        }
    } else {
        const float* in = s == 1 ? w0 : (s == 2 ? w1 : (s == 3 ? w2 : w3));
        u16* out       = s == 1 ? o0 : (s == 2 ? o1 : (s == 3 ? o2 : o3));
        float4 v = *(const float4*)(in + i);
        *(ushort4*)(out + i) = pk4(v.x, v.y, v.z, v.w);
    }
}

// ---------------------------------------------------------------------------
// QKV GEMM (frozen from round 16: double-buffer + prefetch)
// ---------------------------------------------------------------------------
__global__ __launch_bounds__(256) void gemm_qkv(
    const u16* __restrict__ A,
    const u16* __restrict__ W0, const u16* __restrict__ W1, const u16* __restrict__ W2,
    const float* __restrict__ B0, const float* __restrict__ B1, const float* __restrict__ B2,
    u16* __restrict__ O0, u16* __restrict__ O1,
    u16* __restrict__ VT,
    int M, int N, int K)
{
    const int x = blockIdx.x & 7;
    const int L = blockIdx.x >> 3;                 // 0..95
    const int tm = (8 * (x >> 1) + (L & 7)) << 7;  // 32 tm tiles
    const int tnsel = 12 * (x & 1) + (L >> 3);     // 0..23
    const int sel = tnsel >> 3;
    const int tn  = (tnsel & 7) << 7;

    const u16* W      = sel == 0 ? W0 : (sel == 1 ? W1 : W2);
    const float* bias = sel == 0 ? B0 : (sel == 1 ? B1 : B2);
    u16* O            = sel == 0 ? O0 : O1;        // sel==2 -> VT path

    __shared__ __attribute__((aligned(16))) u16 As[2][128 * 64];
    __shared__ __attribute__((aligned(16))) u16 Bs[2][128 * 64];
    u16 (*Tb)[136] = (u16 (*)[136])As;             // union: post-K-loop only

    const int tid  = threadIdx.x;
    const int lane = tid & 63;
    const int w    = tid >> 6;
    const int l15  = lane & 15;
    const int quad = lane >> 4;

    const int wm = (w >> 1) << 6;
    const int wn = (w & 1) << 6;

    f32x4 acc[4][4];
#pragma unroll
    for (int i = 0; i < 4; ++i)
#pragma unroll
        for (int j = 0; j < 4; ++j) acc[i][j] = f32x4{0.f, 0.f, 0.f, 0.f};

    const int lr  = lane >> 3;                     // 0..7
    const int lcc = lane & 7;                      // dest chunk
    const int scc = lcc ^ lr;                      // source chunk (row&7 == lr)
    const u16* Ag = A + (size_t)(tm + 32 * w + lr) * K + scc * 8;
    const u16* Wg = W + (size_t)(tn + 32 * w + lr) * K + scc * 8;
    u16* Al = &As[0][(32 * w + lr) * 64 + lcc * 8];
    u16* Bl = &Bs[0][(32 * w + lr) * 64 + lcc * 8];

#define QKV_STAGE(bi, k0)                                                      \
    do {                                                                       \
        _Pragma("unroll")                                                      \
        for (int m = 0; m < 4; ++m) {                                          \
            async16(Ag + (k0) + (size_t)m * 8 * K, Al + (bi) * 8192 + m * 512);\
            async16(Wg + (k0) + (size_t)m * 8 * K, Bl + (bi) * 8192 + m * 512);\
        }                                                                      \
    } while (0)

    const int nt = K >> 6;                         // 16
    QKV_STAGE(0, 0);
    for (int t = 0; t < nt; ++t) {
        const int cur = t & 1;
        asm volatile("s_waitcnt vmcnt(0)" ::: "memory");
        __syncthreads();
        if (t + 1 < nt) QKV_STAGE(cur ^ 1, (t + 1) * 64);
        const u16* Ab = As[cur];
        const u16* Bb = Bs[cur];
#pragma unroll
        for (int kk = 0; kk < 2; ++kk) {
            bf16x8 a[4], b[4];
#pragma unroll
            for (int i = 0; i < 4; ++i) {
                const int r  = wm + 16 * i + l15;
                const int sl = (kk * 4 + quad) ^ (r & 7);
                a[i] = *(const bf16x8*)&Ab[r * 64 + sl * 8];
            }
#pragma unroll
            for (int j = 0; j < 4; ++j) {
                const int r  = wn + 16 * j + l15;
                const int sl = (kk * 4 + quad) ^ (r & 7);
                b[j] = *(const bf16x8*)&Bb[r * 64 + sl * 8];
            }
#pragma unroll
            for (int i = 0; i < 4; ++i)
#pragma unroll
                for (int j = 0; j < 4; ++j)
                    acc[i][j] = mfma16(a[i], b[j], acc[i][j]);
        }
    }
#undef QKV_STAGE

    if (sel == 2) {
        const int bb = tm >> 11;
        const int s0 = tm & 2047;
        const size_t vtb = ((size_t)bb << 10) + tn;
        for (int c32 = 0; c32 < 128; c32 += 32) {
            __syncthreads();
            if ((c32 >> 6) == (wn >> 6)) {
                const int j0 = (c32 >> 4) & 2;
#pragma unroll
                for (int jj = 0; jj < 2; ++jj) {
                    const int j  = j0 + jj;
                    const int cc = jj * 16 + l15;
                    const float bj = bias[tn + wn + 16 * j + l15];
#pragma unroll
                    for (int i = 0; i < 4; ++i) {
                        const int rr = wm + 16 * i + quad * 4;
                        *(ushort4*)&Tb[cc][rr] =
                            pk4(acc[i][j][0] + bj, acc[i][j][1] + bj,
                                acc[i][j][2] + bj, acc[i][j][3] + bj);
                    }
                }
            }
            __syncthreads();
            {
                const int c  = tid >> 3;
                const int ss = (tid & 7) * 16;
                uint4 v0 = *(const uint4*)&Tb[c][ss];
                uint4 v1 = *(const uint4*)&Tb[c][ss + 8];
                u16* dst = &VT[(vtb + c32 + c) * 2048 + s0 + ss];
                *(uint4*)dst       = v0;
                *(uint4*)(dst + 8) = v1;
            }
        }
    } else {
#pragma unroll
        for (int j = 0; j < 4; ++j) {
            const int col = tn + wn + 16 * j + l15;
            const float bj = bias[col];
#pragma unroll
            for (int i = 0; i < 4; ++i) {
                const int row = tm + wm + 16 * i + quad * 4;
#pragma unroll
                for (int r = 0; r < 4; ++r) {
                    union { float f; unsigned u; } v; v.f = acc[i][j][r] + bj;
                    unsigned rn = v.u + 0x7FFFu + ((v.u >> 16) & 1u);
                    O[(size_t)(row + r) * N + col] = (u16)(rn >> 16);
                }
            }
        }
    }
}

// ---------------------------------------------------------------------------
// Output projection GEMM (frozen from round 16)
// ---------------------------------------------------------------------------
__global__ __launch_bounds__(256) void gemm_out64(
    const u16* __restrict__ A, const u16* __restrict__ W,
    const float* __restrict__ bias, float* __restrict__ O,
    int M, int N, int K)
{
    __shared__ __attribute__((aligned(16))) u16 As[2][128 * 64];
    __shared__ __attribute__((aligned(16))) u16 Bs[2][64 * 64];

    const int x = blockIdx.x & 7;
    const int L = blockIdx.x >> 3;                 // 0..63
    const int tm = (8 * (x >> 1) + (L & 7)) << 7;  // 32 tiles
    const int tn = (8 * (x & 1) + (L >> 3)) << 6;  // 16 tiles

    const int tid  = threadIdx.x;
    const int lane = tid & 63;
    const int w    = tid >> 6;
    const int l15  = lane & 15;
    const int quad = lane >> 4;

    const int wm = (w >> 1) << 6;
    const int wn = (w & 1) << 5;

    f32x4 acc[4][2];
#pragma unroll
    for (int i = 0; i < 4; ++i)
#pragma unroll
        for (int j = 0; j < 2; ++j) acc[i][j] = f32x4{0.f, 0.f, 0.f, 0.f};

    const int lr  = lane >> 3;
    const int lcc = lane & 7;
    const int scc = lcc ^ lr;
    const u16* Ag = A + (size_t)(tm + 32 * w + lr) * K + scc * 8;
    const u16* Wg = W + (size_t)(tn + 16 * w + lr) * K + scc * 8;
    u16* Al = &As[0][(32 * w + lr) * 64 + lcc * 8];
    u16* Bl = &Bs[0][(16 * w + lr) * 64 + lcc * 8];

#define OUT_STAGE(bi, k0)                                                      \
    do {                                                                       \
        _Pragma("unroll")                                                      \
        for (int m = 0; m < 4; ++m)                                            \
            async16(Ag + (k0) + (size_t)m * 8 * K, Al + (bi) * 8192 + m * 512);\
        _Pragma("unroll")                                                      \
        for (int m = 0; m < 2; ++m)                                            \
            async16(Wg + (k0) + (size_t)m * 8 * K, Bl + (bi) * 4096 + m * 512);\
    } while (0)

    const int nt = K >> 6;                         // 16
    OUT_STAGE(0, 0);
    for (int t = 0; t < nt; ++t) {
        const int cur = t & 1;
        asm volatile("s_waitcnt vmcnt(0)" ::: "memory");
        __syncthreads();
        if (t + 1 < nt) OUT_STAGE(cur ^ 1, (t + 1) * 64);
        const u16* Ab = As[cur];
        const u16* Bb = Bs[cur];
#pragma unroll
        for (int kk = 0; kk < 2; ++kk) {
            bf16x8 a[4], b[2];
#pragma unroll
            for (int i = 0; i < 4; ++i) {
                const int r  = wm + 16 * i + l15;
                const int sl = (kk * 4 + quad) ^ (r & 7);
                a[i] = *(const bf16x8*)&Ab[r * 64 + sl * 8];
            }
#pragma unroll
            for (int j = 0; j < 2; ++j) {
                const int r  = wn + 16 * j + l15;
                const int sl = (kk * 4 + quad) ^ (r & 7);
                b[j] = *(const bf16x8*)&Bb[r * 64 + sl * 8];
            }
#pragma unroll
            for (int i = 0; i < 4; ++i)
#pragma unroll
                for (int j = 0; j < 2; ++j)
                    acc[i][j] = mfma16(a[i], b[j], acc[i][j]);
        }
    }
#undef OUT_STAGE

#pragma unroll
    for (int j = 0; j < 2; ++j) {
        const int col = tn + wn + 16 * j + l15;
        const float bj = bias[col];
#pragma unroll
        for (int i = 0; i < 4; ++i) {
            const int row = tm + wm + 16 * i + quad * 4;
#pragma unroll
            for (int r = 0; r < 4; ++r)
                O[(size_t)(row + r) * N + col] = acc[i][j][r] + bj;
        }
    }
}

// ---------------------------------------------------------------------------
// attn10: round-18. KVBLK 64 -> 128 (two 64-sub-tiles per barrier).
//  * One vmcnt(0)+barrier now covers 2x the compute: iteration count 24.5
//    -> ~12.6 avg; per-iteration sync/drain overhead (the dominant cost:
//    no pipe >40% busy) halves.
//  * Within-iteration overlap replaces the cross-iteration T15 carry:
//    QK0 -> exp0 -> QK1 -> PV0 (MFMA) || exp1 (VALU) -> PV1. PV0 and exp1
//    are independent, same barrier-free region -> dual-issue. V stays valid
//    the whole iteration, so double-buffer suffices (triple-buffer dropped).
//  * LDS = K 2x16KB + V 2x16KB + Pt 16KB = 80 KiB -> 2 blocks/CU = 160 KiB
//    exact fit (current allocator shows zero padding).
// ---------------------------------------------------------------------------
__device__ __forceinline__ bf16x8 rdt(const u16* base, int t, int l15, int cc) {
    const int r = t * 16 + l15;
    const int c = (cc & 3) ^ ((r >> 1) & 3);
    return *(const bf16x8*)(base + (cc >> 2) * 2048 + r * 32 + c * 8);
}

#define QK_EXP(Z, PROW, QG, MASKED, RSV, KB)                                   \
    do {                                                                       \
        _Pragma("unroll")                                                      \
        for (int t = 0; t < 4; ++t) {                                          \
            float e0 = fexp2(fmaf((Z)[t][0], SC, -16.0f));                     \
            float e1 = fexp2(fmaf((Z)[t][1], SC, -16.0f));                     \
            float e2 = fexp2(fmaf((Z)[t][2], SC, -16.0f));                     \
            float e3 = fexp2(fmaf((Z)[t][3], SC, -16.0f));                     \
            if (MASKED) {                                                      \
                const int kb = (KB) + t * 16 + quad * 4;                       \
                if (kb + 0 > (QG)) e0 = 0.f;                                   \
                if (kb + 1 > (QG)) e1 = 0.f;                                   \
                if (kb + 2 > (QG)) e2 = 0.f;                                   \
                if (kb + 3 > (QG)) e3 = 0.f;                                   \
            }                                                                  \
            (RSV)[0] += e0; (RSV)[1] += e1;                                    \
            (RSV)[2] += e2; (RSV)[3] += e3;                                    \
            *(ushort4*)((PROW) + (((2 * t + whi) ^ sl7) << 3) + woff) =        \
                pk4(e0, e1, e2, e3);                                           \
        }                                                                      \
    } while (0)

// QK of one 64-sub-tile into registers
#define QK_TILE(ZH, ZL, KTp, DOL)                                              \
    do {                                                                       \
        __builtin_amdgcn_s_setprio(1);                                         \
        if (DOL) {                                                             \
            _Pragma("unroll")                                                  \
            for (int t = 0; t < 4; ++t) {                                      \
                const bf16x8 kA = rdt(KTp, t, l15, quad);                      \
                const bf16x8 kB = rdt(KTp, t, l15, quad + 4);                  \
                f32x4 zh = {0,0,0,0};                                          \
                zh = mfma16(kA, qH0, zh); zh = mfma16(kB, qH1, zh);            \
                (ZH)[t] = zh;                                                  \
                f32x4 zl = {0,0,0,0};                                          \
                zl = mfma16(kA, qL0, zl); zl = mfma16(kB, qL1, zl);            \
                (ZL)[t] = zl;                                                  \
            }                                                                  \
        } else {                                                               \
            _Pragma("unroll")                                                  \
            for (int t = 0; t < 4; ++t) {                                      \
                const bf16x8 kA = rdt(KTp, t, l15, quad);                      \
                const bf16x8 kB = rdt(KTp, t, l15, quad + 4);                  \
                f32x4 zh = {0,0,0,0};                                          \
                zh = mfma16(kA, qH0, zh); zh = mfma16(kB, qH1, zh);            \
                (ZH)[t] = zh;                                                  \
            }                                                                  \
        }                                                                      \
        __builtin_amdgcn_s_setprio(0);                                         \
    } while (0)

// PV of one 64-sub-tile (V frags read once, shared H/L)
#define PV_TILE(VLp, PH0, PH1, PL0, PL1, DOL)                                  \
    do {                                                                       \
        __builtin_amdgcn_s_setprio(1);                                         \
        if (DOL) {                                                             \
            _Pragma("unroll")                                                  \
            for (int t = 0; t < 4; ++t) {                                      \
                const bf16x8 vA = rdt(VLp, t, l15, quad);                      \
                const bf16x8 vB = rdt(VLp, t, l15, quad + 4);                  \
                oH[t] = mfma16(vA, PH0, oH[t]);                                \
                oH[t] = mfma16(vB, PH1, oH[t]);                                \
                oL[t] = mfma16(vA, PL0, oL[t]);                                \
                oL[t] = mfma16(vB, PL1, oL[t]);                                \
            }                                                                  \
        } else {                                                               \
            _Pragma("unroll")                                                  \
            for (int t = 0; t < 4; ++t) {                                      \
                const bf16x8 vA = rdt(VLp, t, l15, quad);                      \
                const bf16x8 vB = rdt(VLp, t, l15, quad + 4);                  \
                oH[t] = mfma16(vA, PH0, oH[t]);                                \
                oH[t] = mfma16(vB, PH1, oH[t]);                                \
            }                                                                  \
        }                                                                      \
        __builtin_amdgcn_s_setprio(0);                                         \
    } while (0)

__global__ __launch_bounds__(256) void attn10(
    const u16* __restrict__ Q, const u16* __restrict__ Kb,
    const u16* __restrict__ VT, u16* __restrict__ ctx)
{
    __shared__ __attribute__((aligned(16))) u16 Kt[2][2][4096];
    __shared__ __attribute__((aligned(16))) u16 Vt[2][2][4096];
    __shared__ __attribute__((aligned(16))) u16 Pt[4][32][64];

    const int tid  = threadIdx.x;
    const int lane = tid & 63;
    const int wid  = tid >> 6;
    const int l15  = lane & 15;
    const int quad = lane >> 4;
    const int sl7  = l15 & 7;
    const int whi  = quad >> 1;
    const int woff = (quad & 1) * 4;

    const int hb = blockIdx.x & 31;
    const int h  = hb & 15, b = hb >> 4;
    const int ti = blockIdx.x >> 5;
    const int g  = (ti < 8) ? ti : 23 - ti;

    const int sL = 4 * g + wid, sH = 127 - sL;
    const int KL = g, KH = 31 - g;
    const int NT = (KH + 2) >> 1;            // 128-tiles

    const size_t rowbase = (size_t)b * 2048;
    const int cbase = h * 64;
    const u16* kbase = Kb + rowbase * 1024 + cbase;
    const u16* vbase = VT + ((size_t)b * 1024 + cbase) * 2048;

    const int qgL = sL * 16 + l15, qgH = sH * 16 + l15;
    const u16* qpL = Q + (rowbase + qgL) * 1024 + cbase + quad * 8;
    const u16* qpH = Q + (rowbase + qgH) * 1024 + cbase + quad * 8;
    const bf16x8 qL0 = *(const bf16x8*)qpL, qL1 = *(const bf16x8*)(qpL + 32);
    const bf16x8 qH0 = *(const bf16x8*)qpH, qH1 = *(const bf16x8*)(qpH + 32);

    // staging: row sr = tid>>2, dest chunk tid&3 (linear); source chunk
    // permuted (c ^ ((sr>>1)&3)) so rdt's 16-lane read phases are 2-way.
    const int sr  = tid >> 2;
    const int sc0 = (((tid & 3) ^ ((sr >> 1) & 3)) << 3);
    const u16* kg = kbase + (size_t)sr * 1024 + sc0;
    const u16* vg = vbase + (size_t)sr * 2048 + sc0;

    f32x4 oL[4], oH[4];
#pragma unroll
    for (int i = 0; i < 4; ++i) { oL[i] = f32x4{0,0,0,0}; oH[i] = f32x4{0,0,0,0}; }
    f32x4 rsLv = {0,0,0,0}, rsHv = {0,0,0,0};
    const float SC = 0.18033688011112042f;

    u16 (*ptw)[64] = Pt[wid];
    u16* const prH = &ptw[16 + l15][0];
    u16* const prL = &ptw[l15][0];
    const int pof0 = (quad ^ sl7) << 3;
    const int pof1 = ((quad | 4) ^ sl7) << 3;

    // stage one 128-tile: K rows [T*128, T*128+128), V cols [T*128, +128)
#define STAGE(buf, Tt)                                                         \
    do {                                                                       \
        const u16* kq = kg + (size_t)(Tt) * 131072;                            \
        const u16* vq = vg + (Tt) * 128;                                       \
        async16(kq,          &Kt[buf][0][tid * 8]);                            \
        async16(kq + 32,     &Kt[buf][0][2048 + tid * 8]);                     \
        async16(kq + 65536,  &Kt[buf][1][tid * 8]);                            \
        async16(kq + 65568,  &Kt[buf][1][2048 + tid * 8]);                     \
        async16(vq,          &Vt[buf][0][tid * 8]);                            \
        async16(vq + 32,     &Vt[buf][0][2048 + tid * 8]);                     \
        async16(vq + 64,     &Vt[buf][1][tid * 8]);                            \
        async16(vq + 96,     &Vt[buf][1][2048 + tid * 8]);                     \
    } while (0)

    STAGE(0, 0);

    for (int T = 0; T < NT; ++T) {
        const int cur = T & 1;
        asm volatile("s_waitcnt vmcnt(0)" ::: "memory");
        __syncthreads();
        if (T + 1 < NT) STAGE(cur ^ 1, T + 1);

        const int k0 = 2 * T, k1 = k0 + 1;
        const bool has1 = (k1 <= KH);
        const bool doL0 = (k0 <= KL), doL1 = (k1 <= KL);
        const bool mH0 = (k0 == KH), mL0 = (k0 == KL);
        const bool mH1 = (k1 == KH), mL1 = (k1 == KL);

        const u16* KT0 = Kt[cur][0];
        const u16* KT1 = Kt[cur][1];
        const u16* VL0 = Vt[cur][0];
        const u16* VL1 = Vt[cur][1];

        // ---- sub0: QK + exp + P-frag ----
        f32x4 zH0[4], zL0[4];
        QK_TILE(zH0, zL0, KT0, doL0);
        if (mH0) QK_EXP(zH0, prH, qgH, 1, rsHv, k0 * 64);
        else     QK_EXP(zH0, prH, qgH, 0, rsHv, k0 * 64);
        if (doL0) {
            if (mL0) QK_EXP(zL0, prL, qgL, 1, rsLv, k0 * 64);
            else     QK_EXP(zL0, prL, qgL, 0, rsLv, k0 * 64);
        }
        bf16x8 p0H0 = *(const bf16x8*)(prH + pof0);
        bf16x8 p0H1 = *(const bf16x8*)(prH + pof1);
        bf16x8 p0L0 = {}, p0L1 = {};
        if (doL0) {
            p0L0 = *(const bf16x8*)(prL + pof0);
            p0L1 = *(const bf16x8*)(prL + pof1);
        }

        // ---- sub1 QK (independent of PV0) ----
        f32x4 zH1[4], zL1[4];
        if (has1) QK_TILE(zH1, zL1, KT1, doL1);

        // ---- PV0 (MFMA) -- exp1 (VALU) below is independent: dual-issue ----
        PV_TILE(VL0, p0H0, p0H1, p0L0, p0L1, doL0);

        // ---- sub1 exp + P-frag + PV ----
        if (has1) {
            if (mH1) QK_EXP(zH1, prH, qgH, 1, rsHv, k1 * 64);
            else     QK_EXP(zH1, prH, qgH, 0, rsHv, k1 * 64);
            if (doL1) {
                if (mL1) QK_EXP(zL1, prL, qgL, 1, rsLv, k1 * 64);
                else     QK_EXP(zL1, prL, qgL, 0, rsLv, k1 * 64);
            }
            bf16x8 p1H0 = *(const bf16x8*)(prH + pof0);
            bf16x8 p1H1 = *(const bf16x8*)(prH + pof1);
            bf16x8 p1L0 = {}, p1L1 = {};
            if (doL1) {
                p1L0 = *(const bf16x8*)(prL + pof0);
                p1L1 = *(const bf16x8*)(prL + pof1);
            }
            PV_TILE(VL1, p1H0, p1H1, p1L0, p1L1, doL1);
        }
    }
#undef STAGE

    float rsH = (rsHv[0] + rsHv[1]) + (rsHv[2] + rsHv[3]);
    float rsL = (rsLv[0] + rsLv[1]) + (rsLv[2] + rsLv[3]);
    rsH += __shfl_xor(rsH, 16); rsH += __shfl_xor(rsH, 32);
    rsL += __shfl_xor(rsL, 16); rsL += __shfl_xor(rsL, 32);
    const float iH = 1.0f / rsH, iL = 1.0f / rsL;
#pragma unroll
    for (int t = 0; t < 4; ++t) {
        *(ushort4*)&ctx[(rowbase + qgL) * 1024 + cbase + t * 16 + quad * 4] =
            pk4(oL[t][0] * iL, oL[t][1] * iL, oL[t][2] * iL, oL[t][3] * iL);
        *(ushort4*)&ctx[(rowbase + qgH) * 1024 + cbase + t * 16 + quad * 4] =
            pk4(oH[t][0] * iH, oH[t][1] * iH, oH[t][2] * iH, oH[t][3] * iH);
    }
}

extern "C" void kernel_launch(void* const* d_in, const int* in_sizes, int n_in,
                              void* d_out, int out_size, void* d_ws, size_t ws_size,
                              hipStream_t stream) {
    const float* x  = (const float*)d_in[0];
    const float* Wq = (const float*)d_in[1];
    const float* bq = (const float*)d_in[2];
    const float* Wk = (const float*)d_in[3];
    const float* bk = (const float*)d_in[4];
    const float* Wv = (const float*)d_in[5];
    const float* bv = (const float*)d_in[6];
    const float* Wo = (const float*)d_in[7];
    const float* bo = (const float*)d_in[8];
    float* out = (float*)d_out;

    const int N = 1024, K = 1024;
    const int M = in_sizes[0] / K;           // 4096
    const size_t MN = (size_t)M * N;
    const size_t WN = (size_t)N * K;

    u16* xb  = (u16*)d_ws;
    u16* wqb = xb  + MN;
    u16* wkb = wqb + WN;
    u16* wvb = wkb + WN;
    u16* wob = wvb + WN;
    u16* q   = wob + WN;
    u16* kb  = q   + MN;
    u16* vt  = kb  + MN;                     // V^T: [b*1024 + h*64 + d][s]
    u16* ctx = q;                            // alias: disjoint per-wave strips

    cast_all<<<dim3(1024, 5), 256, 0, stream>>>(
        x, Wq, Wk, Wv, Wo, xb, wqb, wkb, wvb, wob);

    gemm_qkv<<<dim3(768), 256, 0, stream>>>(
        xb, wqb, wkb, wvb, bq, bk, bv, q, kb, vt, M, N, K);

    attn10<<<dim3(512), 256, 0, stream>>>(q, kb, vt, ctx);

    gemm_out64<<<dim3(512), 256, 0, stream>>>(
        ctx, wob, bo, out, M, N, K);
}

// Round 6
// 178.163 us; speedup vs baseline: 1.1346x; 1.0367x over previous
//
#include <hip/hip_runtime.h>
#include <stdint.h>

typedef unsigned short u16;
typedef __bf16 bf16x8 __attribute__((ext_vector_type(8)));
typedef __bf16 bf16x4v __attribute__((ext_vector_type(4)));
typedef float f32x4 __attribute__((ext_vector_type(4)));

typedef __attribute__((address_space(3))) uint32_t lds_u32;
typedef __attribute__((address_space(1))) uint32_t glb_u32;

__device__ __forceinline__ f32x4 mfma16(bf16x8 a, bf16x8 b, f32x4 c) {
    return __builtin_amdgcn_mfma_f32_16x16x32_bf16(a, b, c, 0, 0, 0);
}

// 4x f32 -> bf16 via native cvt (RNE), reinterpreted as ushort4
__device__ __forceinline__ ushort4 pk4(float a, float b, float c, float d) {
    bf16x4v v;
    v[0] = (__bf16)a; v[1] = (__bf16)b; v[2] = (__bf16)c; v[3] = (__bf16)d;
    union { bf16x4v v; ushort4 u; } cv; cv.v = v; return cv.u;
}

// raw v_exp_f32 (skip ocml wrapper)
__device__ __forceinline__ float fexp2(float x) {
    return __builtin_amdgcn_exp2f(x);
}

// async global->LDS, 16B per lane (LDS dest = wave base + lane*16)
__device__ __forceinline__ void async16(const u16* g, u16* l) {
    __builtin_amdgcn_global_load_lds((glb_u32*)(uintptr_t)(const void*)g,
                                     (lds_u32*)l, 16, 0, 0);
}

// ---------------------------------------------------------------------------
// fp32 -> bf16 casts (unchanged)
// ---------------------------------------------------------------------------
__global__ __launch_bounds__(256) void cast_all(
    const float* __restrict__ x,
    const float* __restrict__ w0, const float* __restrict__ w1,
    const float* __restrict__ w2, const float* __restrict__ w3,
    u16* __restrict__ xo, u16* __restrict__ o0, u16* __restrict__ o1,
    u16* __restrict__ o2, u16* __restrict__ o3)
{
    const int s = blockIdx.y;
    const int i = (blockIdx.x * 256 + threadIdx.x) * 4;
    if (s == 0) {
#pragma unroll
        for (int c = 0; c < 4; ++c) {
            const int j = i + c * (1 << 20);
            float4 v = *(const float4*)(x + j);
            *(ushort4*)(xo + j) = pk4(v.x, v.y, v.z, v.w);
        }
    } else {
        const float* in = s == 1 ? w0 : (s == 2 ? w1 : (s == 3 ? w2 : w3));
        u16* out       = s == 1 ? o0 : (s == 2 ? o1 : (s == 3 ? o2 : o3));
        float4 v = *(const float4*)(in + i);
        *(ushort4*)(out + i) = pk4(v.x, v.y, v.z, v.w);
    }
}

// ---------------------------------------------------------------------------
// QKV GEMM (frozen from round 16: double-buffer + prefetch)
// ---------------------------------------------------------------------------
__global__ __launch_bounds__(256) void gemm_qkv(
    const u16* __restrict__ A,
    const u16* __restrict__ W0, const u16* __restrict__ W1, const u16* __restrict__ W2,
    const float* __restrict__ B0, const float* __restrict__ B1, const float* __restrict__ B2,
    u16* __restrict__ O0, u16* __restrict__ O1,
    u16* __restrict__ VT,
    int M, int N, int K)
{
    const int x = blockIdx.x & 7;
    const int L = blockIdx.x >> 3;                 // 0..95
    const int tm = (8 * (x >> 1) + (L & 7)) << 7;  // 32 tm tiles
    const int tnsel = 12 * (x & 1) + (L >> 3);     // 0..23
    const int sel = tnsel >> 3;
    const int tn  = (tnsel & 7) << 7;

    const u16* W      = sel == 0 ? W0 : (sel == 1 ? W1 : W2);
    const float* bias = sel == 0 ? B0 : (sel == 1 ? B1 : B2);
    u16* O            = sel == 0 ? O0 : O1;        // sel==2 -> VT path

    __shared__ __attribute__((aligned(16))) u16 As[2][128 * 64];
    __shared__ __attribute__((aligned(16))) u16 Bs[2][128 * 64];
    u16 (*Tb)[136] = (u16 (*)[136])As;             // union: post-K-loop only

    const int tid  = threadIdx.x;
    const int lane = tid & 63;
    const int w    = tid >> 6;
    const int l15  = lane & 15;
    const int quad = lane >> 4;

    const int wm = (w >> 1) << 6;
    const int wn = (w & 1) << 6;

    f32x4 acc[4][4];
#pragma unroll
    for (int i = 0; i < 4; ++i)
#pragma unroll
        for (int j = 0; j < 4; ++j) acc[i][j] = f32x4{0.f, 0.f, 0.f, 0.f};

    const int lr  = lane >> 3;                     // 0..7
    const int lcc = lane & 7;                      // dest chunk
    const int scc = lcc ^ lr;                      // source chunk (row&7 == lr)
    const u16* Ag = A + (size_t)(tm + 32 * w + lr) * K + scc * 8;
    const u16* Wg = W + (size_t)(tn + 32 * w + lr) * K + scc * 8;
    u16* Al = &As[0][(32 * w + lr) * 64 + lcc * 8];
    u16* Bl = &Bs[0][(32 * w + lr) * 64 + lcc * 8];

#define QKV_STAGE(bi, k0)                                                      \
    do {                                                                       \
        _Pragma("unroll")                                                      \
        for (int m = 0; m < 4; ++m) {                                          \
            async16(Ag + (k0) + (size_t)m * 8 * K, Al + (bi) * 8192 + m * 512);\
            async16(Wg + (k0) + (size_t)m * 8 * K, Bl + (bi) * 8192 + m * 512);\
        }                                                                      \
    } while (0)

    const int nt = K >> 6;                         // 16
    QKV_STAGE(0, 0);
    for (int t = 0; t < nt; ++t) {
        const int cur = t & 1;
        asm volatile("s_waitcnt vmcnt(0)" ::: "memory");
        __syncthreads();
        if (t + 1 < nt) QKV_STAGE(cur ^ 1, (t + 1) * 64);
        const u16* Ab = As[cur];
        const u16* Bb = Bs[cur];
#pragma unroll
        for (int kk = 0; kk < 2; ++kk) {
            bf16x8 a[4], b[4];
#pragma unroll
            for (int i = 0; i < 4; ++i) {
                const int r  = wm + 16 * i + l15;
                const int sl = (kk * 4 + quad) ^ (r & 7);
                a[i] = *(const bf16x8*)&Ab[r * 64 + sl * 8];
            }
#pragma unroll
            for (int j = 0; j < 4; ++j) {
                const int r  = wn + 16 * j + l15;
                const int sl = (kk * 4 + quad) ^ (r & 7);
                b[j] = *(const bf16x8*)&Bb[r * 64 + sl * 8];
            }
#pragma unroll
            for (int i = 0; i < 4; ++i)
#pragma unroll
                for (int j = 0; j < 4; ++j)
                    acc[i][j] = mfma16(a[i], b[j], acc[i][j]);
        }
    }
#undef QKV_STAGE

    if (sel == 2) {
        const int bb = tm >> 11;
        const int s0 = tm & 2047;
        const size_t vtb = ((size_t)bb << 10) + tn;
        for (int c32 = 0; c32 < 128; c32 += 32) {
            __syncthreads();
            if ((c32 >> 6) == (wn >> 6)) {
                const int j0 = (c32 >> 4) & 2;
#pragma unroll
                for (int jj = 0; jj < 2; ++jj) {
                    const int j  = j0 + jj;
                    const int cc = jj * 16 + l15;
                    const float bj = bias[tn + wn + 16 * j + l15];
#pragma unroll
                    for (int i = 0; i < 4; ++i) {
                        const int rr = wm + 16 * i + quad * 4;
                        *(ushort4*)&Tb[cc][rr] =
                            pk4(acc[i][j][0] + bj, acc[i][j][1] + bj,
                                acc[i][j][2] + bj, acc[i][j][3] + bj);
                    }
                }
            }
            __syncthreads();
            {
                const int c  = tid >> 3;
                const int ss = (tid & 7) * 16;
                uint4 v0 = *(const uint4*)&Tb[c][ss];
                uint4 v1 = *(const uint4*)&Tb[c][ss + 8];
                u16* dst = &VT[(vtb + c32 + c) * 2048 + s0 + ss];
                *(uint4*)dst       = v0;
                *(uint4*)(dst + 8) = v1;
            }
        }
    } else {
#pragma unroll
        for (int j = 0; j < 4; ++j) {
            const int col = tn + wn + 16 * j + l15;
            const float bj = bias[col];
#pragma unroll
            for (int i = 0; i < 4; ++i) {
                const int row = tm + wm + 16 * i + quad * 4;
#pragma unroll
                for (int r = 0; r < 4; ++r) {
                    union { float f; unsigned u; } v; v.f = acc[i][j][r] + bj;
                    unsigned rn = v.u + 0x7FFFu + ((v.u >> 16) & 1u);
                    O[(size_t)(row + r) * N + col] = (u16)(rn >> 16);
                }
            }
        }
    }
}

// ---------------------------------------------------------------------------
// Output projection GEMM (frozen from round 16)
// ---------------------------------------------------------------------------
__global__ __launch_bounds__(256) void gemm_out64(
    const u16* __restrict__ A, const u16* __restrict__ W,
    const float* __restrict__ bias, float* __restrict__ O,
    int M, int N, int K)
{
    __shared__ __attribute__((aligned(16))) u16 As[2][128 * 64];
    __shared__ __attribute__((aligned(16))) u16 Bs[2][64 * 64];

    const int x = blockIdx.x & 7;
    const int L = blockIdx.x >> 3;                 // 0..63
    const int tm = (8 * (x >> 1) + (L & 7)) << 7;  // 32 tiles
    const int tn = (8 * (x & 1) + (L >> 3)) << 6;  // 16 tiles

    const int tid  = threadIdx.x;
    const int lane = tid & 63;
    const int w    = tid >> 6;
    const int l15  = lane & 15;
    const int quad = lane >> 4;

    const int wm = (w >> 1) << 6;
    const int wn = (w & 1) << 5;

    f32x4 acc[4][2];
#pragma unroll
    for (int i = 0; i < 4; ++i)
#pragma unroll
        for (int j = 0; j < 2; ++j) acc[i][j] = f32x4{0.f, 0.f, 0.f, 0.f};

    const int lr  = lane >> 3;
    const int lcc = lane & 7;
    const int scc = lcc ^ lr;
    const u16* Ag = A + (size_t)(tm + 32 * w + lr) * K + scc * 8;
    const u16* Wg = W + (size_t)(tn + 16 * w + lr) * K + scc * 8;
    u16* Al = &As[0][(32 * w + lr) * 64 + lcc * 8];
    u16* Bl = &Bs[0][(16 * w + lr) * 64 + lcc * 8];

#define OUT_STAGE(bi, k0)                                                      \
    do {                                                                       \
        _Pragma("unroll")                                                      \
        for (int m = 0; m < 4; ++m)                                            \
            async16(Ag + (k0) + (size_t)m * 8 * K, Al + (bi) * 8192 + m * 512);\
        _Pragma("unroll")                                                      \
        for (int m = 0; m < 2; ++m)                                            \
            async16(Wg + (k0) + (size_t)m * 8 * K, Bl + (bi) * 4096 + m * 512);\
    } while (0)

    const int nt = K >> 6;                         // 16
    OUT_STAGE(0, 0);
    for (int t = 0; t < nt; ++t) {
        const int cur = t & 1;
        asm volatile("s_waitcnt vmcnt(0)" ::: "memory");
        __syncthreads();
        if (t + 1 < nt) OUT_STAGE(cur ^ 1, (t + 1) * 64);
        const u16* Ab = As[cur];
        const u16* Bb = Bs[cur];
#pragma unroll
        for (int kk = 0; kk < 2; ++kk) {
            bf16x8 a[4], b[2];
#pragma unroll
            for (int i = 0; i < 4; ++i) {
                const int r  = wm + 16 * i + l15;
                const int sl = (kk * 4 + quad) ^ (r & 7);
                a[i] = *(const bf16x8*)&Ab[r * 64 + sl * 8];
            }
#pragma unroll
            for (int j = 0; j < 2; ++j) {
                const int r  = wn + 16 * j + l15;
                const int sl = (kk * 4 + quad) ^ (r & 7);
                b[j] = *(const bf16x8*)&Bb[r * 64 + sl * 8];
            }
#pragma unroll
            for (int i = 0; i < 4; ++i)
#pragma unroll
                for (int j = 0; j < 2; ++j)
                    acc[i][j] = mfma16(a[i], b[j], acc[i][j]);
        }
    }
#undef OUT_STAGE

#pragma unroll
    for (int j = 0; j < 2; ++j) {
        const int col = tn + wn + 16 * j + l15;
        const float bj = bias[col];
#pragma unroll
        for (int i = 0; i < 4; ++i) {
            const int row = tm + wm + 16 * i + quad * 4;
#pragma unroll
            for (int r = 0; r < 4; ++r)
                O[(size_t)(row + r) * N + col] = acc[i][j][r] + bj;
        }
    }
}

// ---------------------------------------------------------------------------
// attn11: round-19 occupancy restructure. One Q-group (16 rows) per wave.
//  * Grid 512 -> 1024 blocks (4096 waves = 16 waves/CU, 2x TLP). The prior
//    structure was latency-bound at 2 waves/SIMD with every pipe <=50% busy;
//    wave count was capped by the 2-groups-per-wave decomposition.
//  * Block = 4 waves owning groups 4*g4..4*g4+3 -> ALL waves share the same
//    diagonal tile count (s>>2 == g4): zero intra-block idle.
//  * LDS: K dbuf 16K + V dbuf 16K + Pt 8K = 40 KiB -> 4 blocks/CU (160 exact).
//  * Quartile snake: g4 = {to, 15-to, 16+to, 31-to}; co-resident tile sets
//    {ti, ti+8, ti+16, ti+24} sum to 66 tiles -> balanced CUs. hb in low bits
//    keeps co-resident blocks on the same (b,h) for K/V L2 reuse.
//  * __launch_bounds__(256,4) caps VGPR at 128 to guarantee 4 blocks/CU.
// ---------------------------------------------------------------------------
__device__ __forceinline__ bf16x8 rdt(const u16* base, int t, int l15, int cc) {
    const int r = t * 16 + l15;
    const int c = (cc & 3) ^ ((r >> 1) & 3);
    return *(const bf16x8*)(base + (cc >> 2) * 2048 + r * 32 + c * 8);
}

#define QK_EXP(Z, PROW, QG, MASKED, RSV, KB)                                   \
    do {                                                                       \
        _Pragma("unroll")                                                      \
        for (int t = 0; t < 4; ++t) {                                          \
            float e0 = fexp2(fmaf((Z)[t][0], SC, -16.0f));                     \
            float e1 = fexp2(fmaf((Z)[t][1], SC, -16.0f));                     \
            float e2 = fexp2(fmaf((Z)[t][2], SC, -16.0f));                     \
            float e3 = fexp2(fmaf((Z)[t][3], SC, -16.0f));                     \
            if (MASKED) {                                                      \
                const int kb = (KB) + t * 16 + quad * 4;                       \
                if (kb + 0 > (QG)) e0 = 0.f;                                   \
                if (kb + 1 > (QG)) e1 = 0.f;                                   \
                if (kb + 2 > (QG)) e2 = 0.f;                                   \
                if (kb + 3 > (QG)) e3 = 0.f;                                   \
            }                                                                  \
            (RSV)[0] += e0; (RSV)[1] += e1;                                    \
            (RSV)[2] += e2; (RSV)[3] += e3;                                    \
            *(ushort4*)((PROW) + (((2 * t + whi) ^ sl7) << 3) + woff) =        \
                pk4(e0, e1, e2, e3);                                           \
        }                                                                      \
    } while (0)

__global__ __launch_bounds__(256, 4) void attn11(
    const u16* __restrict__ Q, const u16* __restrict__ Kb,
    const u16* __restrict__ VT, u16* __restrict__ ctx)
{
    __shared__ __attribute__((aligned(16))) u16 Kt[2][4096];
    __shared__ __attribute__((aligned(16))) u16 Vt[2][4096];
    __shared__ __attribute__((aligned(16))) u16 Pt[4][16][64];

    const int tid  = threadIdx.x;
    const int lane = tid & 63;
    const int wid  = tid >> 6;
    const int l15  = lane & 15;
    const int quad = lane >> 4;
    const int sl7  = l15 & 7;
    const int whi  = quad >> 1;
    const int woff = (quad & 1) * 4;

    const int hb = blockIdx.x & 31;
    const int h  = hb & 15, b = hb >> 4;
    const int ti = blockIdx.x >> 5;          // 0..31
    const int tq = ti >> 3, to = ti & 7;
    const int g4 = (tq == 0) ? to
                 : (tq == 1) ? (15 - to)
                 : (tq == 2) ? (16 + to)
                 :             (31 - to);    // quartet index 0..31
    const int s  = 4 * g4 + wid;             // Q group 0..127
    const int NT = g4 + 1;                   // KV 64-tiles (same for all waves)

    const size_t rowbase = (size_t)b * 2048;
    const int cbase = h * 64;
    const u16* kbase = Kb + rowbase * 1024 + cbase;
    const u16* vbase = VT + ((size_t)b * 1024 + cbase) * 2048;

    const int qg = s * 16 + l15;
    const u16* qp = Q + (rowbase + qg) * 1024 + cbase + quad * 8;
    const bf16x8 q0 = *(const bf16x8*)qp, q1 = *(const bf16x8*)(qp + 32);

    // staging: row sr = tid>>2, dest chunk tid&3 (linear); source chunk
    // permuted (c ^ ((sr>>1)&3)) so rdt's 16-lane read phases are 2-way.
    const int sr  = tid >> 2;
    const int sc0 = (((tid & 3) ^ ((sr >> 1) & 3)) << 3);
    const u16* kg = kbase + (size_t)sr * 1024 + sc0;
    const u16* vg = vbase + (size_t)sr * 2048 + sc0;

    f32x4 o[4];
#pragma unroll
    for (int i = 0; i < 4; ++i) o[i] = f32x4{0, 0, 0, 0};
    f32x4 rsv = {0, 0, 0, 0};
    const float SC = 0.18033688011112042f;

    u16 (*ptw)[64] = Pt[wid];
    u16* const pr = &ptw[l15][0];
    const int pof0 = (quad ^ sl7) << 3;
    const int pof1 = ((quad | 4) ^ sl7) << 3;

#define STAGE(buf, Tt)                                                         \
    do {                                                                       \
        const u16* kq = kg + (size_t)(Tt) * 65536;                             \
        const u16* vq = vg + (Tt) * 64;                                        \
        async16(kq,      &Kt[buf][tid * 8]);                                   \
        async16(kq + 32, &Kt[buf][2048 + tid * 8]);                            \
        async16(vq,      &Vt[buf][tid * 8]);                                   \
        async16(vq + 32, &Vt[buf][2048 + tid * 8]);                            \
    } while (0)

    STAGE(0, 0);

    for (int T = 0; T < NT; ++T) {
        const int cur = T & 1;
        asm volatile("s_waitcnt vmcnt(0)" ::: "memory");
        __syncthreads();
        if (T + 1 < NT) STAGE(cur ^ 1, T + 1);

        const u16* KT = Kt[cur];
        const u16* VL = Vt[cur];

        // ---- QK^T ----
        f32x4 z[4];
        __builtin_amdgcn_s_setprio(1);
#pragma unroll
        for (int t = 0; t < 4; ++t) {
            const bf16x8 kA = rdt(KT, t, l15, quad);
            const bf16x8 kB = rdt(KT, t, l15, quad + 4);
            f32x4 zz = {0, 0, 0, 0};
            zz = mfma16(kA, q0, zz);
            zz = mfma16(kB, q1, zz);
            z[t] = zz;
        }
        __builtin_amdgcn_s_setprio(0);

        // ---- exp + pack (mask only on the diagonal tile) ----
        if (T == NT - 1) QK_EXP(z, pr, qg, 1, rsv, T * 64);
        else             QK_EXP(z, pr, qg, 0, rsv, T * 64);

        // ---- P fragments ----
        const bf16x8 pb0 = *(const bf16x8*)(pr + pof0);
        const bf16x8 pb1 = *(const bf16x8*)(pr + pof1);

        // ---- PV ----
        __builtin_amdgcn_s_setprio(1);
#pragma unroll
        for (int t = 0; t < 4; ++t) {
            const bf16x8 vA = rdt(VL, t, l15, quad);
            const bf16x8 vB = rdt(VL, t, l15, quad + 4);
            o[t] = mfma16(vA, pb0, o[t]);
            o[t] = mfma16(vB, pb1, o[t]);
        }
        __builtin_amdgcn_s_setprio(0);
    }
#undef STAGE

    float rs = (rsv[0] + rsv[1]) + (rsv[2] + rsv[3]);
    rs += __shfl_xor(rs, 16); rs += __shfl_xor(rs, 32);
    const float inv = 1.0f / rs;
#pragma unroll
    for (int t = 0; t < 4; ++t) {
        *(ushort4*)&ctx[(rowbase + qg) * 1024 + cbase + t * 16 + quad * 4] =
            pk4(o[t][0] * inv, o[t][1] * inv, o[t][2] * inv, o[t][3] * inv);
    }
}

extern "C" void kernel_launch(void* const* d_in, const int* in_sizes, int n_in,
                              void* d_out, int out_size, void* d_ws, size_t ws_size,
                              hipStream_t stream) {
    const float* x  = (const float*)d_in[0];
    const float* Wq = (const float*)d_in[1];
    const float* bq = (const float*)d_in[2];
    const float* Wk = (const float*)d_in[3];
    const float* bk = (const float*)d_in[4];
    const float* Wv = (const float*)d_in[5];
    const float* bv = (const float*)d_in[6];
    const float* Wo = (const float*)d_in[7];
    const float* bo = (const float*)d_in[8];
    float* out = (float*)d_out;

    const int N = 1024, K = 1024;
    const int M = in_sizes[0] / K;           // 4096
    const size_t MN = (size_t)M * N;
    const size_t WN = (size_t)N * K;

    u16* xb  = (u16*)d_ws;
    u16* wqb = xb  + MN;
    u16* wkb = wqb + WN;
    u16* wvb = wkb + WN;
    u16* wob = wvb + WN;
    u16* q   = wob + WN;
    u16* kb  = q   + MN;
    u16* vt  = kb  + MN;                     // V^T: [b*1024 + h*64 + d][s]
    u16* ctx = q;                            // alias: disjoint per-wave strips

    cast_all<<<dim3(1024, 5), 256, 0, stream>>>(
        x, Wq, Wk, Wv, Wo, xb, wqb, wkb, wvb, wob);

    gemm_qkv<<<dim3(768), 256, 0, stream>>>(
        xb, wqb, wkb, wvb, bq, bk, bv, q, kb, vt, M, N, K);

    attn11<<<dim3(1024), 256, 0, stream>>>(q, kb, vt, ctx);

    gemm_out64<<<dim3(512), 256, 0, stream>>>(
        ctx, wob, bo, out, M, N, K);
}